// Round 1
// baseline (1289.119 us; speedup 1.0000x reference)
//
#include <hip/hip_runtime.h>
#include <hip/hip_bf16.h>

// ---------------------------------------------------------------------------
// RESK2 4-layer GCN on MI355X.
// Pipeline per call:
//   build CSR by tgt (hist -> scan -> fill permuted (src,w))
//   L0: gemm128(x,W0,b0)->H ; agg128(H)->XA (relu)
//   L1: gemm128(XA,W1,b1)->H; agg128(H)->XB (relu)
//   L2: gemm128(XB,W2,b2)->H; agg128(H)+XA->XB (relu+resid)
//   L3: gemm40(XB,W3,b3)->H ; agg40(H)->d_out ; log_softmax in place
// ---------------------------------------------------------------------------

__global__ __launch_bounds__(256) void k_zero(int* __restrict__ p, int n) {
    int i = blockIdx.x * 256 + threadIdx.x;
    if (i < n) p[i] = 0;
}

__global__ __launch_bounds__(256) void k_hist(const int* __restrict__ tgt,
                                              int* __restrict__ deg, int E) {
    int e = blockIdx.x * 256 + threadIdx.x;
    if (e < E) atomicAdd(&deg[tgt[e]], 1);
}

// chunk = 4096 elements per block (16 per thread)
__global__ __launch_bounds__(256) void k_scan1(const int* __restrict__ deg,
                                               int* __restrict__ partial, int N) {
    __shared__ int sm[256];
    int tid = threadIdx.x;
    int base = blockIdx.x * 4096;
    int s = 0;
    for (int i = tid; i < 4096; i += 256) {
        int idx = base + i;
        s += (idx < N) ? deg[idx] : 0;
    }
    sm[tid] = s;
    __syncthreads();
    for (int off = 128; off > 0; off >>= 1) {
        if (tid < off) sm[tid] += sm[tid + off];
        __syncthreads();
    }
    if (tid == 0) partial[blockIdx.x] = sm[0];
}

__global__ void k_scan2(int* __restrict__ partial, int n) {
    if (threadIdx.x == 0 && blockIdx.x == 0) {
        int acc = 0;
        for (int i = 0; i < n; i++) { int v = partial[i]; partial[i] = acc; acc += v; }
    }
}

__global__ __launch_bounds__(256) void k_scan3(const int* __restrict__ deg,
                                               const int* __restrict__ partial,
                                               int* __restrict__ rowptr,
                                               int* __restrict__ cursor, int N, int E) {
    __shared__ int sm[256];
    int tid = threadIdx.x;
    int base = blockIdx.x * 4096 + tid * 16;
    int v[16];
    int tot = 0;
#pragma unroll
    for (int j = 0; j < 16; j++) {
        int idx = base + j;
        v[j] = (idx < N) ? deg[idx] : 0;
        tot += v[j];
    }
    sm[tid] = tot;
    __syncthreads();
    // Hillis-Steele inclusive scan over 256 thread totals
    for (int off = 1; off < 256; off <<= 1) {
        int t = (tid >= off) ? sm[tid - off] : 0;
        __syncthreads();
        sm[tid] += t;
        __syncthreads();
    }
    int run = partial[blockIdx.x] + sm[tid] - tot;  // exclusive prefix
#pragma unroll
    for (int j = 0; j < 16; j++) {
        int idx = base + j;
        if (idx < N) {
            rowptr[idx] = run;
            cursor[idx] = run;
            run += v[j];
        }
    }
    if (blockIdx.x == 0 && tid == 0) rowptr[N] = E;
}

__global__ __launch_bounds__(256) void k_fill(const int* __restrict__ src,
                                              const int* __restrict__ tgt,
                                              const float* __restrict__ ew,
                                              int* __restrict__ cursor,
                                              int2* __restrict__ perm, int E) {
    int e = blockIdx.x * 256 + threadIdx.x;
    if (e < E) {
        int t = tgt[e];
        int p = atomicAdd(&cursor[t], 1);
        perm[p] = make_int2(src[e], __float_as_int(ew[e]));
    }
}

// ---------------------------------------------------------------------------
// GEMM: C[N,128] = A[N,K] @ W[K,128] + b.  BM=128, BN=128, BK=32, 256 thr,
// 8x8 micro-tile per thread.
// ---------------------------------------------------------------------------
template <int K>
__global__ __launch_bounds__(256) void k_gemm128(const float* __restrict__ A,
                                                 const float* __restrict__ W,
                                                 const float* __restrict__ bias,
                                                 float* __restrict__ C, int N) {
    __shared__ float As[128][33];   // [row][k], +1 pad: broadcast-friendly reads
    __shared__ float Ws[32 * 128];  // [k][col]

    const int tid = threadIdx.x;
    const int rowBase = blockIdx.x * 128;
    const int cx = tid & 15;   // cols cx*8 .. cx*8+7
    const int ry = tid >> 4;   // rows ry*8 .. ry*8+7

    float acc[8][8] = {};

    for (int k0 = 0; k0 < K; k0 += 32) {
        // stage A tile (128 rows x 32 k), float4 per thread x4
#pragma unroll
        for (int i = 0; i < 4; i++) {
            int flat4 = i * 256 + tid;          // 0..1023
            int r = flat4 >> 3;                 // 0..127
            int k4 = flat4 & 7;                 // 0..7
            int rg = rowBase + r;
            rg = rg < N ? rg : N - 1;           // clamp (rows >= N never stored)
            float4 v = *(const float4*)&A[(size_t)rg * K + k0 + k4 * 4];
            As[r][k4 * 4 + 0] = v.x;
            As[r][k4 * 4 + 1] = v.y;
            As[r][k4 * 4 + 2] = v.z;
            As[r][k4 * 4 + 3] = v.w;
        }
        // stage W tile (32 x 128 contiguous)
#pragma unroll
        for (int i = 0; i < 4; i++) {
            int flat4 = i * 256 + tid;  // 0..1023 float4s
            float4 v = *(const float4*)&W[(size_t)k0 * 128 + flat4 * 4];
            *(float4*)&Ws[flat4 * 4] = v;
        }
        __syncthreads();

#pragma unroll 4
        for (int kk = 0; kk < 32; kk++) {
            float a[8];
#pragma unroll
            for (int r = 0; r < 8; r++) a[r] = As[ry * 8 + r][kk];
            const float4 w0 = *(const float4*)&Ws[kk * 128 + cx * 8];
            const float4 w1 = *(const float4*)&Ws[kk * 128 + cx * 8 + 4];
#pragma unroll
            for (int r = 0; r < 8; r++) {
                acc[r][0] += a[r] * w0.x;
                acc[r][1] += a[r] * w0.y;
                acc[r][2] += a[r] * w0.z;
                acc[r][3] += a[r] * w0.w;
                acc[r][4] += a[r] * w1.x;
                acc[r][5] += a[r] * w1.y;
                acc[r][6] += a[r] * w1.z;
                acc[r][7] += a[r] * w1.w;
            }
        }
        __syncthreads();
    }

    // epilogue: + bias, store
#pragma unroll
    for (int r = 0; r < 8; r++) {
        int row = rowBase + ry * 8 + r;
        if (row < N) {
            float4 o0, o1;
            o0.x = acc[r][0] + bias[cx * 8 + 0];
            o0.y = acc[r][1] + bias[cx * 8 + 1];
            o0.z = acc[r][2] + bias[cx * 8 + 2];
            o0.w = acc[r][3] + bias[cx * 8 + 3];
            o1.x = acc[r][4] + bias[cx * 8 + 4];
            o1.y = acc[r][5] + bias[cx * 8 + 5];
            o1.z = acc[r][6] + bias[cx * 8 + 6];
            o1.w = acc[r][7] + bias[cx * 8 + 7];
            *(float4*)&C[(size_t)row * 128 + cx * 8] = o0;
            *(float4*)&C[(size_t)row * 128 + cx * 8 + 4] = o1;
        }
    }
}

// C[N,40] = A[N,128] @ W[128,40] + b.  One wave per row; W fully in LDS.
__global__ __launch_bounds__(256) void k_gemm40(const float* __restrict__ A,
                                                const float* __restrict__ W,
                                                const float* __restrict__ bias,
                                                float* __restrict__ C, int N) {
    __shared__ float Ws[128 * 40];
    __shared__ float bs[40];
    int tid = threadIdx.x;
    for (int i = tid; i < 128 * 40 / 4; i += 256)
        ((float4*)Ws)[i] = ((const float4*)W)[i];
    if (tid < 40) bs[tid] = bias[tid];
    __syncthreads();

    int w = tid >> 6;
    int lane = tid & 63;
    int row = blockIdx.x * 4 + w;
    if (row >= N) return;
    int cl = lane < 40 ? lane : 0;

    float acc = bs[cl];
    const float4* arow = (const float4*)&A[(size_t)row * 128];
#pragma unroll 4
    for (int k4 = 0; k4 < 32; k4++) {
        float4 a = arow[k4];  // wave-uniform
        acc += a.x * Ws[(k4 * 4 + 0) * 40 + cl];
        acc += a.y * Ws[(k4 * 4 + 1) * 40 + cl];
        acc += a.z * Ws[(k4 * 4 + 2) * 40 + cl];
        acc += a.w * Ws[(k4 * 4 + 3) * 40 + cl];
    }
    if (lane < 40) C[(size_t)row * 40 + lane] = acc;
}

// ---------------------------------------------------------------------------
// Pull aggregation (CSR by tgt): one wave per node, F=128 (float2 per lane).
// out = [relu](sum_e w_e * h[src_e]) [+ resid]
// ---------------------------------------------------------------------------
__global__ __launch_bounds__(256) void k_agg128(const float* __restrict__ h,
                                                const int* __restrict__ rowptr,
                                                const int2* __restrict__ perm,
                                                const float* __restrict__ resid,
                                                float* __restrict__ out, int N,
                                                int do_relu) {
    int node = (blockIdx.x * 256 + threadIdx.x) >> 6;
    if (node >= N) return;
    int lane = threadIdx.x & 63;
    int beg = rowptr[node], end = rowptr[node + 1];
    float ax = 0.f, ay = 0.f;
    for (int e = beg; e < end; e++) {
        int2 sw = perm[e];
        float wt = __int_as_float(sw.y);
        float2 v = *(const float2*)&h[(size_t)sw.x * 128 + lane * 2];
        ax += v.x * wt;
        ay += v.y * wt;
    }
    if (do_relu) {
        ax = fmaxf(ax, 0.f);
        ay = fmaxf(ay, 0.f);
    }
    size_t o = (size_t)node * 128 + lane * 2;
    if (resid) {
        ax += resid[o];
        ay += resid[o + 1];
    }
    *(float2*)&out[o] = make_float2(ax, ay);
}

// F=40 variant (final layer), writes logits to out
__global__ __launch_bounds__(256) void k_agg40(const float* __restrict__ h,
                                               const int* __restrict__ rowptr,
                                               const int2* __restrict__ perm,
                                               float* __restrict__ out, int N) {
    int node = (blockIdx.x * 256 + threadIdx.x) >> 6;
    if (node >= N) return;
    int lane = threadIdx.x & 63;
    int cl = lane < 40 ? lane : 0;
    int beg = rowptr[node], end = rowptr[node + 1];
    float acc = 0.f;
    for (int e = beg; e < end; e++) {
        int2 sw = perm[e];
        acc += __int_as_float(sw.y) * h[(size_t)sw.x * 40 + cl];
    }
    if (lane < 40) out[(size_t)node * 40 + lane] = acc;
}

__global__ __launch_bounds__(256) void k_logsoftmax(float* __restrict__ out, int N) {
    int node = (blockIdx.x * 256 + threadIdx.x) >> 6;
    if (node >= N) return;
    int lane = threadIdx.x & 63;
    float x = (lane < 40) ? out[(size_t)node * 40 + lane] : -__builtin_inff();
    float m = x;
#pragma unroll
    for (int off = 32; off > 0; off >>= 1) m = fmaxf(m, __shfl_xor(m, off, 64));
    float ex = (lane < 40) ? expf(x - m) : 0.f;
    float s = ex;
#pragma unroll
    for (int off = 32; off > 0; off >>= 1) s += __shfl_xor(s, off, 64);
    float ls = logf(s);
    if (lane < 40) out[(size_t)node * 40 + lane] = x - m - ls;
}

extern "C" void kernel_launch(void* const* d_in, const int* in_sizes, int n_in,
                              void* d_out, int out_size, void* d_ws, size_t ws_size,
                              hipStream_t stream) {
    const float* x  = (const float*)d_in[0];
    const int*   src = (const int*)d_in[1];
    const int*   tgt = (const int*)d_in[2];
    const float* ew  = (const float*)d_in[3];
    const float* W0 = (const float*)d_in[4];
    const float* b0 = (const float*)d_in[5];
    const float* W1 = (const float*)d_in[6];
    const float* b1 = (const float*)d_in[7];
    const float* W2 = (const float*)d_in[8];
    const float* b2 = (const float*)d_in[9];
    const float* W3 = (const float*)d_in[10];
    const float* b3 = (const float*)d_in[11];

    const int N = in_sizes[0] / 256;
    const int E = in_sizes[1];

    char* ws = (char*)d_ws;
    size_t off = 0;
    auto alloc = [&](size_t bytes) -> void* {
        void* p = ws + off;
        off = (off + bytes + 255) & ~(size_t)255;
        return p;
    };
    float* H      = (float*)alloc((size_t)N * 128 * 4);
    float* XA     = (float*)alloc((size_t)N * 128 * 4);
    float* XB     = (float*)alloc((size_t)N * 128 * 4);
    int*   deg    = (int*)alloc((size_t)N * 4);
    int*   rowptr = (int*)alloc((size_t)(N + 1) * 4);
    int*   cursor = (int*)alloc((size_t)N * 4);
    int*   partial= (int*)alloc(64 * 4);
    int2*  perm   = (int2*)alloc((size_t)E * 8);
    (void)ws_size;

    const int nChunk = (N + 4095) / 4096;
    float* logits = (float*)d_out;

    // CSR build
    k_zero<<<(N + 255) / 256, 256, 0, stream>>>(deg, N);
    k_hist<<<(E + 255) / 256, 256, 0, stream>>>(tgt, deg, E);
    k_scan1<<<nChunk, 256, 0, stream>>>(deg, partial, N);
    k_scan2<<<1, 64, 0, stream>>>(partial, nChunk);
    k_scan3<<<nChunk, 256, 0, stream>>>(deg, partial, rowptr, cursor, N, E);
    k_fill<<<(E + 255) / 256, 256, 0, stream>>>(src, tgt, ew, cursor, perm, E);

    const int gGemm = (N + 127) / 128;
    const int gWave = (N + 3) / 4;  // wave-per-node kernels, 4 waves/block

    // L0
    k_gemm128<256><<<gGemm, 256, 0, stream>>>(x, W0, b0, H, N);
    k_agg128<<<gWave, 256, 0, stream>>>(H, rowptr, perm, nullptr, XA, N, 1);
    // L1
    k_gemm128<128><<<gGemm, 256, 0, stream>>>(XA, W1, b1, H, N);
    k_agg128<<<gWave, 256, 0, stream>>>(H, rowptr, perm, nullptr, XB, N, 1);
    // L2 (+residual XA)
    k_gemm128<128><<<gGemm, 256, 0, stream>>>(XB, W2, b2, H, N);
    k_agg128<<<gWave, 256, 0, stream>>>(H, rowptr, perm, XA, XB, N, 1);
    // L3
    k_gemm40<<<gWave, 256, 0, stream>>>(XB, W3, b3, H, N);
    k_agg40<<<gWave, 256, 0, stream>>>(H, rowptr, perm, logits, N);
    k_logsoftmax<<<gWave, 256, 0, stream>>>(logits, N);
}

// Round 2
// 849.006 us; speedup vs baseline: 1.5184x; 1.5184x over previous
//
#include <hip/hip_runtime.h>
#include <hip/hip_bf16.h>

// ---------------------------------------------------------------------------
// RESK2 4-layer GCN on MI355X — round 2.
// bf16 everywhere between ops (fp32 accumulate), MFMA GEMMs, fused softmax.
//   CSR build (unchanged)
//   x -> bf16; W0..W2 -> bf16 transposed [col][K]
//   L0: mfma_gemm<256>(Xb,Wt0,b0)->Hb ; agg128(Hb)->XAb (bf16, relu)
//   L1: mfma_gemm<128>(XAb,Wt1,b1)->Hb; agg128(Hb)->XBb (bf16, relu)
//   L2: mfma_gemm<128>(XBb,Wt2,b2)->Hb; agg128(Hb)+XAb->XBf (fp32, relu+resid)
//   L3: gemm40(XBf,W3,b3)->H40b (bf16); agg40+log_softmax fused -> d_out
// ---------------------------------------------------------------------------

typedef __attribute__((ext_vector_type(8))) short short8;
typedef __attribute__((ext_vector_type(4))) float float4v;

static __device__ __forceinline__ float bf2f_lo(unsigned int v) {
    return __uint_as_float(v << 16);
}
static __device__ __forceinline__ float bf2f_hi(unsigned int v) {
    return __uint_as_float(v & 0xffff0000u);
}
static __device__ __forceinline__ unsigned short f2bf(float f) {
    unsigned int u = __float_as_uint(f);
    u = (u + 0x7fffu + ((u >> 16) & 1u)) >> 16;  // RNE
    return (unsigned short)u;
}

// ------------------------------- CSR build --------------------------------
__global__ __launch_bounds__(256) void k_zero(int* __restrict__ p, int n) {
    int i = blockIdx.x * 256 + threadIdx.x;
    if (i < n) p[i] = 0;
}

__global__ __launch_bounds__(256) void k_hist(const int* __restrict__ tgt,
                                              int* __restrict__ deg, int E) {
    int e = blockIdx.x * 256 + threadIdx.x;
    if (e < E) atomicAdd(&deg[tgt[e]], 1);
}

__global__ __launch_bounds__(256) void k_scan1(const int* __restrict__ deg,
                                               int* __restrict__ partial, int N) {
    __shared__ int sm[256];
    int tid = threadIdx.x;
    int base = blockIdx.x * 4096;
    int s = 0;
    for (int i = tid; i < 4096; i += 256) {
        int idx = base + i;
        s += (idx < N) ? deg[idx] : 0;
    }
    sm[tid] = s;
    __syncthreads();
    for (int off = 128; off > 0; off >>= 1) {
        if (tid < off) sm[tid] += sm[tid + off];
        __syncthreads();
    }
    if (tid == 0) partial[blockIdx.x] = sm[0];
}

__global__ void k_scan2(int* __restrict__ partial, int n) {
    if (threadIdx.x == 0 && blockIdx.x == 0) {
        int acc = 0;
        for (int i = 0; i < n; i++) { int v = partial[i]; partial[i] = acc; acc += v; }
    }
}

__global__ __launch_bounds__(256) void k_scan3(const int* __restrict__ deg,
                                               const int* __restrict__ partial,
                                               int* __restrict__ rowptr,
                                               int* __restrict__ cursor, int N, int E) {
    __shared__ int sm[256];
    int tid = threadIdx.x;
    int base = blockIdx.x * 4096 + tid * 16;
    int v[16];
    int tot = 0;
#pragma unroll
    for (int j = 0; j < 16; j++) {
        int idx = base + j;
        v[j] = (idx < N) ? deg[idx] : 0;
        tot += v[j];
    }
    sm[tid] = tot;
    __syncthreads();
    for (int off = 1; off < 256; off <<= 1) {
        int t = (tid >= off) ? sm[tid - off] : 0;
        __syncthreads();
        sm[tid] += t;
        __syncthreads();
    }
    int run = partial[blockIdx.x] + sm[tid] - tot;
#pragma unroll
    for (int j = 0; j < 16; j++) {
        int idx = base + j;
        if (idx < N) {
            rowptr[idx] = run;
            cursor[idx] = run;
            run += v[j];
        }
    }
    if (blockIdx.x == 0 && tid == 0) rowptr[N] = E;
}

__global__ __launch_bounds__(256) void k_fill(const int* __restrict__ src,
                                              const int* __restrict__ tgt,
                                              const float* __restrict__ ew,
                                              int* __restrict__ cursor,
                                              int2* __restrict__ perm, int E) {
    int e = blockIdx.x * 256 + threadIdx.x;
    if (e < E) {
        int t = tgt[e];
        int p = atomicAdd(&cursor[t], 1);
        perm[p] = make_int2(src[e], __float_as_int(ew[e]));
    }
}

// ----------------------------- dtype prep ---------------------------------
__global__ __launch_bounds__(256) void k_cast_bf16(const float* __restrict__ s,
                                                   unsigned short* __restrict__ d, int n) {
    int i = (blockIdx.x * 256 + threadIdx.x) * 4;
    if (i + 3 < n) {
        float4 v = *(const float4*)&s[i];
        unsigned int a = (unsigned int)f2bf(v.x) | ((unsigned int)f2bf(v.y) << 16);
        unsigned int b = (unsigned int)f2bf(v.z) | ((unsigned int)f2bf(v.w) << 16);
        *(uint2*)&d[i] = make_uint2(a, b);
    } else {
        for (int j = i; j < n; j++) d[j] = f2bf(s[j]);
    }
}

// W [K][C] fp32 -> Wt [C][K] bf16
__global__ __launch_bounds__(256) void k_wtrans(const float* __restrict__ W,
                                                unsigned short* __restrict__ Wt,
                                                int K, int C) {
    int idx = blockIdx.x * 256 + threadIdx.x;
    if (idx < K * C) {
        int k = idx / C, c = idx % C;
        Wt[(size_t)c * K + k] = f2bf(W[idx]);
    }
}

// ---------------------------------------------------------------------------
// MFMA GEMM: C[N,128](bf16) = A[N,K](bf16) @ W[K,128] + b, W pre-transposed
// as Wt[128][K] bf16. 128x128 tile / block, 4 waves, wave = 32 rows x 128 cols,
// 16 mfma_f32_16x16x32_bf16 per k-step. LDS rows padded to 40 shorts (80 B)
// -> quad reads hit 8 banks / 2-way (free).
// ---------------------------------------------------------------------------
template <int K>
__global__ __launch_bounds__(256) void k_gemm_mfma(const unsigned short* __restrict__ A,
                                                   const unsigned short* __restrict__ Wt,
                                                   const float* __restrict__ bias,
                                                   unsigned short* __restrict__ C, int N) {
    __shared__ unsigned short As[128 * 40];
    __shared__ unsigned short Bs[128 * 40];
    const int tid = threadIdx.x;
    const int wave = tid >> 6, lane = tid & 63;
    const int quad = lane >> 4, l15 = lane & 15;
    const int rowBase = blockIdx.x * 128;

    const float4v z = {0.f, 0.f, 0.f, 0.f};
    float4v acc[2][8];
#pragma unroll
    for (int i = 0; i < 2; i++)
#pragma unroll
        for (int j = 0; j < 8; j++) acc[i][j] = z;

    for (int k0 = 0; k0 < K; k0 += 32) {
#pragma unroll
        for (int i = 0; i < 2; i++) {
            int t = i * 256 + tid;  // 0..511 chunks of 8 bf16 (16 B)
            int r = t >> 2;         // 0..127
            int kc = t & 3;         // 0..3
            int rg = rowBase + r;
            rg = rg < N ? rg : N - 1;
            uint4 va = *(const uint4*)&A[(size_t)rg * K + k0 + kc * 8];
            *(uint4*)&As[r * 40 + kc * 8] = va;
            uint4 vb = *(const uint4*)&Wt[(size_t)r * K + k0 + kc * 8];
            *(uint4*)&Bs[r * 40 + kc * 8] = vb;
        }
        __syncthreads();

        // a-frag: lane holds A[m=l15][k=quad*8+j] ; b-frag: B[k=quad*8+j][n=l15]
        short8 a0 = *(const short8*)&As[(wave * 32 + l15) * 40 + quad * 8];
        short8 a1 = *(const short8*)&As[(wave * 32 + 16 + l15) * 40 + quad * 8];
#pragma unroll
        for (int c = 0; c < 8; c++) {
            short8 b = *(const short8*)&Bs[(c * 16 + l15) * 40 + quad * 8];
            acc[0][c] = __builtin_amdgcn_mfma_f32_16x16x32_bf16(a0, b, acc[0][c], 0, 0, 0);
            acc[1][c] = __builtin_amdgcn_mfma_f32_16x16x32_bf16(a1, b, acc[1][c], 0, 0, 0);
        }
        __syncthreads();
    }

    // C/D layout: col = l15, row = quad*4 + i  (verified mapping)
#pragma unroll
    for (int rt = 0; rt < 2; rt++) {
#pragma unroll
        for (int c = 0; c < 8; c++) {
            int col = c * 16 + l15;
            float bv = bias[col];
#pragma unroll
            for (int i = 0; i < 4; i++) {
                int row = rowBase + wave * 32 + rt * 16 + quad * 4 + i;
                if (row < N) C[(size_t)row * 128 + col] = f2bf(acc[rt][c][i] + bv);
            }
        }
    }
}

// C[N,64-stride](bf16, cols<40 valid) = A[N,128](fp32) @ W[128,40] + b.
__global__ __launch_bounds__(256) void k_gemm40(const float* __restrict__ A,
                                                const float* __restrict__ W,
                                                const float* __restrict__ bias,
                                                unsigned short* __restrict__ C, int N) {
    __shared__ float Ws[128 * 40];
    __shared__ float bs[40];
    int tid = threadIdx.x;
    for (int i = tid; i < 128 * 40 / 4; i += 256)
        ((float4*)Ws)[i] = ((const float4*)W)[i];
    if (tid < 40) bs[tid] = bias[tid];
    __syncthreads();

    int w = tid >> 6;
    int lane = tid & 63;
    int row = blockIdx.x * 4 + w;
    if (row >= N) return;
    int cl = lane < 40 ? lane : 0;

    float acc = bs[cl];
    const float4* arow = (const float4*)&A[(size_t)row * 128];
#pragma unroll 4
    for (int k4 = 0; k4 < 32; k4++) {
        float4 a = arow[k4];
        acc += a.x * Ws[(k4 * 4 + 0) * 40 + cl];
        acc += a.y * Ws[(k4 * 4 + 1) * 40 + cl];
        acc += a.z * Ws[(k4 * 4 + 2) * 40 + cl];
        acc += a.w * Ws[(k4 * 4 + 3) * 40 + cl];
    }
    if (lane < 40) C[(size_t)row * 64 + lane] = f2bf(acc);
}

// ---------------------------------------------------------------------------
// Pull aggregation, F=128 bf16 gather table; one wave per node; 4x unroll.
// out = relu(sum w*h[src]) [+ resid];  OUTF32: fp32 out, else bf16 out.
// ---------------------------------------------------------------------------
template <int OUTF32>
__global__ __launch_bounds__(256) void k_agg128(const unsigned short* __restrict__ h,
                                                const int* __restrict__ rowptr,
                                                const int2* __restrict__ perm,
                                                const unsigned short* __restrict__ resid,
                                                void* __restrict__ outv, int N) {
    int node = (blockIdx.x * 256 + threadIdx.x) >> 6;
    if (node >= N) return;
    int lane = threadIdx.x & 63;
    int beg = rowptr[node], end = rowptr[node + 1];
    float ax0 = 0.f, ay0 = 0.f, ax1 = 0.f, ay1 = 0.f;
    int e = beg;
    for (; e + 3 < end; e += 4) {
        int2 p0 = perm[e], p1 = perm[e + 1], p2 = perm[e + 2], p3 = perm[e + 3];
        unsigned int v0 = *(const unsigned int*)&h[(size_t)p0.x * 128 + lane * 2];
        unsigned int v1 = *(const unsigned int*)&h[(size_t)p1.x * 128 + lane * 2];
        unsigned int v2 = *(const unsigned int*)&h[(size_t)p2.x * 128 + lane * 2];
        unsigned int v3 = *(const unsigned int*)&h[(size_t)p3.x * 128 + lane * 2];
        float w0 = __int_as_float(p0.y), w1 = __int_as_float(p1.y);
        float w2 = __int_as_float(p2.y), w3 = __int_as_float(p3.y);
        ax0 = fmaf(bf2f_lo(v0), w0, ax0); ay0 = fmaf(bf2f_hi(v0), w0, ay0);
        ax1 = fmaf(bf2f_lo(v1), w1, ax1); ay1 = fmaf(bf2f_hi(v1), w1, ay1);
        ax0 = fmaf(bf2f_lo(v2), w2, ax0); ay0 = fmaf(bf2f_hi(v2), w2, ay0);
        ax1 = fmaf(bf2f_lo(v3), w3, ax1); ay1 = fmaf(bf2f_hi(v3), w3, ay1);
    }
    for (; e < end; e++) {
        int2 p = perm[e];
        unsigned int v = *(const unsigned int*)&h[(size_t)p.x * 128 + lane * 2];
        float w = __int_as_float(p.y);
        ax0 = fmaf(bf2f_lo(v), w, ax0);
        ay0 = fmaf(bf2f_hi(v), w, ay0);
    }
    float ax = fmaxf(ax0 + ax1, 0.f);
    float ay = fmaxf(ay0 + ay1, 0.f);
    if (resid) {
        unsigned int rv = *(const unsigned int*)&resid[(size_t)node * 128 + lane * 2];
        ax += bf2f_lo(rv);
        ay += bf2f_hi(rv);
    }
    if (OUTF32) {
        *(float2*)&((float*)outv)[(size_t)node * 128 + lane * 2] = make_float2(ax, ay);
    } else {
        unsigned int o = (unsigned int)f2bf(ax) | ((unsigned int)f2bf(ay) << 16);
        *(unsigned int*)&((unsigned short*)outv)[(size_t)node * 128 + lane * 2] = o;
    }
}

// Final layer: gather h40 (bf16, stride 64) + log_softmax fused. fp32 out.
__global__ __launch_bounds__(256) void k_agg40_lsm(const unsigned short* __restrict__ h,
                                                   const int* __restrict__ rowptr,
                                                   const int2* __restrict__ perm,
                                                   float* __restrict__ out, int N) {
    int node = (blockIdx.x * 256 + threadIdx.x) >> 6;
    if (node >= N) return;
    int lane = threadIdx.x & 63;
    int cl = lane < 40 ? lane : 0;
    int beg = rowptr[node], end = rowptr[node + 1];
    float a0 = 0.f, a1 = 0.f;
    int e = beg;
    for (; e + 3 < end; e += 4) {
        int2 p0 = perm[e], p1 = perm[e + 1], p2 = perm[e + 2], p3 = perm[e + 3];
        float v0 = __uint_as_float((unsigned int)h[(size_t)p0.x * 64 + cl] << 16);
        float v1 = __uint_as_float((unsigned int)h[(size_t)p1.x * 64 + cl] << 16);
        float v2 = __uint_as_float((unsigned int)h[(size_t)p2.x * 64 + cl] << 16);
        float v3 = __uint_as_float((unsigned int)h[(size_t)p3.x * 64 + cl] << 16);
        a0 = fmaf(v0, __int_as_float(p0.y), a0);
        a1 = fmaf(v1, __int_as_float(p1.y), a1);
        a0 = fmaf(v2, __int_as_float(p2.y), a0);
        a1 = fmaf(v3, __int_as_float(p3.y), a1);
    }
    for (; e < end; e++) {
        int2 p = perm[e];
        float v = __uint_as_float((unsigned int)h[(size_t)p.x * 64 + cl] << 16);
        a0 = fmaf(v, __int_as_float(p.y), a0);
    }
    float acc = a0 + a1;

    float x = (lane < 40) ? acc : -__builtin_inff();
    float m = x;
#pragma unroll
    for (int off = 32; off > 0; off >>= 1) m = fmaxf(m, __shfl_xor(m, off, 64));
    float ex = (lane < 40) ? expf(x - m) : 0.f;
    float s = ex;
#pragma unroll
    for (int off = 32; off > 0; off >>= 1) s += __shfl_xor(s, off, 64);
    float ls = logf(s);
    if (lane < 40) out[(size_t)node * 40 + lane] = x - m - ls;
}

extern "C" void kernel_launch(void* const* d_in, const int* in_sizes, int n_in,
                              void* d_out, int out_size, void* d_ws, size_t ws_size,
                              hipStream_t stream) {
    const float* x  = (const float*)d_in[0];
    const int*   src = (const int*)d_in[1];
    const int*   tgt = (const int*)d_in[2];
    const float* ew  = (const float*)d_in[3];
    const float* W0 = (const float*)d_in[4];
    const float* b0 = (const float*)d_in[5];
    const float* W1 = (const float*)d_in[6];
    const float* b1 = (const float*)d_in[7];
    const float* W2 = (const float*)d_in[8];
    const float* b2 = (const float*)d_in[9];
    const float* W3 = (const float*)d_in[10];
    const float* b3 = (const float*)d_in[11];

    const int N = in_sizes[0] / 256;
    const int E = in_sizes[1];

    char* ws = (char*)d_ws;
    size_t off = 0;
    auto alloc = [&](size_t bytes) -> void* {
        void* p = ws + off;
        off = (off + bytes + 255) & ~(size_t)255;
        return p;
    };
    // Xb (bf16, N*256) aliases XBf (fp32, N*128): Xb dead after L0 gemm.
    char* buf0 = (char*)alloc((size_t)N * 256 * 2);
    unsigned short* Xb  = (unsigned short*)buf0;
    float*          XBf = (float*)buf0;
    unsigned short* Hb  = (unsigned short*)alloc((size_t)N * 128 * 2);
    // XAb aliases H40b: XAb dead after L2 agg, H40b written after.
    char* buf1 = (char*)alloc((size_t)N * 128 * 2);
    unsigned short* XAb  = (unsigned short*)buf1;
    unsigned short* H40b = (unsigned short*)buf1;
    unsigned short* XBb  = (unsigned short*)alloc((size_t)N * 128 * 2);
    int*   deg    = (int*)alloc((size_t)N * 4);
    int*   rowptr = (int*)alloc((size_t)(N + 1) * 4);
    int*   cursor = (int*)alloc((size_t)N * 4);
    int*   partial= (int*)alloc(64 * 4);
    int2*  perm   = (int2*)alloc((size_t)E * 8);
    unsigned short* Wt0 = (unsigned short*)alloc(256 * 128 * 2);
    unsigned short* Wt1 = (unsigned short*)alloc(128 * 128 * 2);
    unsigned short* Wt2 = (unsigned short*)alloc(128 * 128 * 2);
    (void)ws_size;

    const int nChunk = (N + 4095) / 4096;
    float* logits = (float*)d_out;

    // CSR build
    k_zero<<<(N + 255) / 256, 256, 0, stream>>>(deg, N);
    k_hist<<<(E + 255) / 256, 256, 0, stream>>>(tgt, deg, E);
    k_scan1<<<nChunk, 256, 0, stream>>>(deg, partial, N);
    k_scan2<<<1, 64, 0, stream>>>(partial, nChunk);
    k_scan3<<<nChunk, 256, 0, stream>>>(deg, partial, rowptr, cursor, N, E);
    k_fill<<<(E + 255) / 256, 256, 0, stream>>>(src, tgt, ew, cursor, perm, E);

    // dtype prep
    const int nx = N * 256;
    k_cast_bf16<<<(nx / 4 + 255) / 256, 256, 0, stream>>>(x, Xb, nx);
    k_wtrans<<<(256 * 128 + 255) / 256, 256, 0, stream>>>(W0, Wt0, 256, 128);
    k_wtrans<<<(128 * 128 + 255) / 256, 256, 0, stream>>>(W1, Wt1, 128, 128);
    k_wtrans<<<(128 * 128 + 255) / 256, 256, 0, stream>>>(W2, Wt2, 128, 128);

    const int gGemm = (N + 127) / 128;
    const int gWave = (N + 3) / 4;

    // L0
    k_gemm_mfma<256><<<gGemm, 256, 0, stream>>>(Xb, Wt0, b0, Hb, N);
    k_agg128<0><<<gWave, 256, 0, stream>>>(Hb, rowptr, perm, nullptr, XAb, N);
    // L1
    k_gemm_mfma<128><<<gGemm, 256, 0, stream>>>(XAb, Wt1, b1, Hb, N);
    k_agg128<0><<<gWave, 256, 0, stream>>>(Hb, rowptr, perm, nullptr, XBb, N);
    // L2 (+residual XAb), fp32 out for gemm40
    k_gemm_mfma<128><<<gGemm, 256, 0, stream>>>(XBb, Wt2, b2, Hb, N);
    k_agg128<1><<<gWave, 256, 0, stream>>>(Hb, rowptr, perm, XAb, XBf, N);
    // L3
    k_gemm40<<<gWave, 256, 0, stream>>>(XBf, W3, b3, H40b, N);
    k_agg40_lsm<<<gWave, 256, 0, stream>>>(H40b, rowptr, perm, logits, N);
}

// Round 3
// 742.812 us; speedup vs baseline: 1.7355x; 1.1430x over previous
//
#include <hip/hip_runtime.h>
#include <hip/hip_bf16.h>

// ---------------------------------------------------------------------------
// RESK2 4-layer GCN on MI355X — round 3.
//   CSR build: hist -> scan -> bucketed 2-phase fill (L2-friendly scatter)
//   L0: mfma_gemm<256>(Xb,Wt0,b0)->Hb ; agg128->XAb (bf16, relu)
//   L1: mfma_gemm<128>(XAb,Wt1,b1)->Hb; agg128->XBb (bf16, relu)
//   L2: mfma_gemm<128>(XBb,Wt2,b2)->Hb; agg128+XAb->XCb (bf16, relu+resid)
//   L3: mfma gemm40(XCb,Wt3,b3)->H40b ; agg40+log_softmax -> d_out
// ---------------------------------------------------------------------------

typedef __attribute__((ext_vector_type(8))) short short8;
typedef __attribute__((ext_vector_type(4))) float float4v;

static __device__ __forceinline__ float bf2f_lo(unsigned int v) {
    return __uint_as_float(v << 16);
}
static __device__ __forceinline__ float bf2f_hi(unsigned int v) {
    return __uint_as_float(v & 0xffff0000u);
}
static __device__ __forceinline__ unsigned short f2bf(float f) {
    unsigned int u = __float_as_uint(f);
    u = (u + 0x7fffu + ((u >> 16) & 1u)) >> 16;  // RNE
    return (unsigned short)u;
}

// ------------------------------- CSR build --------------------------------
__global__ __launch_bounds__(256) void k_zero(int* __restrict__ p, int n) {
    int i = blockIdx.x * 256 + threadIdx.x;
    if (i < n) p[i] = 0;
}

__global__ __launch_bounds__(256) void k_hist(const int* __restrict__ tgt,
                                              int* __restrict__ deg, int E) {
    int e = blockIdx.x * 256 + threadIdx.x;
    if (e < E) atomicAdd(&deg[tgt[e]], 1);
}

__global__ __launch_bounds__(256) void k_scan1(const int* __restrict__ deg,
                                               int* __restrict__ partial, int N) {
    __shared__ int sm[256];
    int tid = threadIdx.x;
    int base = blockIdx.x * 4096;
    int s = 0;
    for (int i = tid; i < 4096; i += 256) {
        int idx = base + i;
        s += (idx < N) ? deg[idx] : 0;
    }
    sm[tid] = s;
    __syncthreads();
    for (int off = 128; off > 0; off >>= 1) {
        if (tid < off) sm[tid] += sm[tid + off];
        __syncthreads();
    }
    if (tid == 0) partial[blockIdx.x] = sm[0];
}

__global__ void k_scan2(int* __restrict__ partial, int n) {
    if (threadIdx.x == 0 && blockIdx.x == 0) {
        int acc = 0;
        for (int i = 0; i < n; i++) { int v = partial[i]; partial[i] = acc; acc += v; }
    }
}

__global__ __launch_bounds__(256) void k_scan3(const int* __restrict__ deg,
                                               const int* __restrict__ partial,
                                               int* __restrict__ rowptr,
                                               int* __restrict__ cursor, int N, int E) {
    __shared__ int sm[256];
    int tid = threadIdx.x;
    int base = blockIdx.x * 4096 + tid * 16;
    int v[16];
    int tot = 0;
#pragma unroll
    for (int j = 0; j < 16; j++) {
        int idx = base + j;
        v[j] = (idx < N) ? deg[idx] : 0;
        tot += v[j];
    }
    sm[tid] = tot;
    __syncthreads();
    for (int off = 1; off < 256; off <<= 1) {
        int t = (tid >= off) ? sm[tid - off] : 0;
        __syncthreads();
        sm[tid] += t;
        __syncthreads();
    }
    int run = partial[blockIdx.x] + sm[tid] - tot;
#pragma unroll
    for (int j = 0; j < 16; j++) {
        int idx = base + j;
        if (idx < N) {
            rowptr[idx] = run;
            cursor[idx] = run;
            run += v[j];
        }
    }
    if (blockIdx.x == 0 && tid == 0) rowptr[N] = E;
}

// chunkCur[c*32] = rowptr[min(c*4096,N)]  (padded: one counter per 128B line)
__global__ void k_chunkinit(const int* __restrict__ rowptr, int* __restrict__ chunkCur,
                            int NC, int N) {
    int c = threadIdx.x;
    if (c < NC) {
        int n0 = c * 4096;
        chunkCur[c * 32] = rowptr[n0 < N ? n0 : N];
    }
}

// Phase A: bucket 1024 edges/block by tgt>>12 into staging (dense per-chunk runs)
__global__ __launch_bounds__(256) void k_bucket(const int* __restrict__ src,
                                                const int* __restrict__ tgt,
                                                const float* __restrict__ ew,
                                                int* __restrict__ chunkCur,
                                                int2* __restrict__ st_srcw,
                                                int* __restrict__ st_tgt, int E) {
    __shared__ int cnt[32];
    __shared__ int base[32];
    __shared__ int rk[32];
    const int tid = threadIdx.x;
    const int e0 = blockIdx.x * 1024 + tid * 4;

    if (tid < 32) { cnt[tid] = 0; rk[tid] = 0; }
    __syncthreads();

    int t4[4], s4[4], w4[4], c4[4];
    bool full = (e0 + 3 < E);
    if (full) {
        int4 tv = *(const int4*)&tgt[e0];
        int4 sv = *(const int4*)&src[e0];
        float4 wv = *(const float4*)&ew[e0];
        t4[0] = tv.x; t4[1] = tv.y; t4[2] = tv.z; t4[3] = tv.w;
        s4[0] = sv.x; s4[1] = sv.y; s4[2] = sv.z; s4[3] = sv.w;
        w4[0] = __float_as_int(wv.x); w4[1] = __float_as_int(wv.y);
        w4[2] = __float_as_int(wv.z); w4[3] = __float_as_int(wv.w);
    } else {
#pragma unroll
        for (int j = 0; j < 4; j++) {
            int e = e0 + j;
            t4[j] = (e < E) ? tgt[e] : -1;
            s4[j] = (e < E) ? src[e] : 0;
            w4[j] = (e < E) ? __float_as_int(ew[e]) : 0;
        }
    }
#pragma unroll
    for (int j = 0; j < 4; j++) {
        c4[j] = t4[j] >> 12;
        if (t4[j] >= 0) atomicAdd(&cnt[c4[j]], 1);
    }
    __syncthreads();
    if (tid < 32) {
        int c = cnt[tid];
        base[tid] = c ? atomicAdd(&chunkCur[tid * 32], c) : 0;
    }
    __syncthreads();
#pragma unroll
    for (int j = 0; j < 4; j++) {
        if (t4[j] >= 0) {
            int r = atomicAdd(&rk[c4[j]], 1);
            int pos = base[c4[j]] + r;
            st_srcw[pos] = make_int2(s4[j], w4[j]);
            st_tgt[pos] = t4[j];
        }
    }
}

// Phase B: linear sweep; final scatter confined to per-chunk L2 windows
__global__ __launch_bounds__(256) void k_fill2(const int2* __restrict__ st_srcw,
                                               const int* __restrict__ st_tgt,
                                               int* __restrict__ cursor,
                                               int2* __restrict__ perm, int E) {
    int e = blockIdx.x * 256 + threadIdx.x;
    if (e < E) {
        int t = st_tgt[e];
        int p = atomicAdd(&cursor[t], 1);
        perm[p] = st_srcw[e];
    }
}

// ----------------------------- dtype prep ---------------------------------
__global__ __launch_bounds__(256) void k_cast_bf16(const float* __restrict__ s,
                                                   unsigned short* __restrict__ d, int n) {
    int i = (blockIdx.x * 256 + threadIdx.x) * 4;
    if (i + 3 < n) {
        float4 v = *(const float4*)&s[i];
        unsigned int a = (unsigned int)f2bf(v.x) | ((unsigned int)f2bf(v.y) << 16);
        unsigned int b = (unsigned int)f2bf(v.z) | ((unsigned int)f2bf(v.w) << 16);
        *(uint2*)&d[i] = make_uint2(a, b);
    } else {
        for (int j = i; j < n; j++) d[j] = f2bf(s[j]);
    }
}

// W [K][C] fp32 -> Wt [C][K] bf16
__global__ __launch_bounds__(256) void k_wtrans(const float* __restrict__ W,
                                                unsigned short* __restrict__ Wt,
                                                int K, int C) {
    int idx = blockIdx.x * 256 + threadIdx.x;
    if (idx < K * C) {
        int k = idx / C, c = idx % C;
        Wt[(size_t)c * K + k] = f2bf(W[idx]);
    }
}

// W3 [128][40] fp32 -> Wt3 [48][128] bf16 (cols 40..47 zero)
__global__ __launch_bounds__(256) void k_wtrans40(const float* __restrict__ W,
                                                  unsigned short* __restrict__ Wt) {
    int idx = blockIdx.x * 256 + threadIdx.x;  // 48*128
    if (idx < 48 * 128) {
        int c = idx >> 7, k = idx & 127;
        Wt[idx] = (c < 40) ? f2bf(W[k * 40 + c]) : 0;
    }
}

// ---------------------------------------------------------------------------
// MFMA GEMM: C[N,128](bf16) = A[N,K](bf16) @ Wt[128][K] + b. 128x128/block.
// ---------------------------------------------------------------------------
template <int K>
__global__ __launch_bounds__(256) void k_gemm_mfma(const unsigned short* __restrict__ A,
                                                   const unsigned short* __restrict__ Wt,
                                                   const float* __restrict__ bias,
                                                   unsigned short* __restrict__ C, int N) {
    __shared__ unsigned short As[128 * 40];
    __shared__ unsigned short Bs[128 * 40];
    const int tid = threadIdx.x;
    const int wave = tid >> 6, lane = tid & 63;
    const int quad = lane >> 4, l15 = lane & 15;
    const int rowBase = blockIdx.x * 128;

    const float4v z = {0.f, 0.f, 0.f, 0.f};
    float4v acc[2][8];
#pragma unroll
    for (int i = 0; i < 2; i++)
#pragma unroll
        for (int j = 0; j < 8; j++) acc[i][j] = z;

    for (int k0 = 0; k0 < K; k0 += 32) {
#pragma unroll
        for (int i = 0; i < 2; i++) {
            int t = i * 256 + tid;
            int r = t >> 2;
            int kc = t & 3;
            int rg = rowBase + r;
            rg = rg < N ? rg : N - 1;
            uint4 va = *(const uint4*)&A[(size_t)rg * K + k0 + kc * 8];
            *(uint4*)&As[r * 40 + kc * 8] = va;
            uint4 vb = *(const uint4*)&Wt[(size_t)r * K + k0 + kc * 8];
            *(uint4*)&Bs[r * 40 + kc * 8] = vb;
        }
        __syncthreads();

        short8 a0 = *(const short8*)&As[(wave * 32 + l15) * 40 + quad * 8];
        short8 a1 = *(const short8*)&As[(wave * 32 + 16 + l15) * 40 + quad * 8];
#pragma unroll
        for (int c = 0; c < 8; c++) {
            short8 b = *(const short8*)&Bs[(c * 16 + l15) * 40 + quad * 8];
            acc[0][c] = __builtin_amdgcn_mfma_f32_16x16x32_bf16(a0, b, acc[0][c], 0, 0, 0);
            acc[1][c] = __builtin_amdgcn_mfma_f32_16x16x32_bf16(a1, b, acc[1][c], 0, 0, 0);
        }
        __syncthreads();
    }

#pragma unroll
    for (int rt = 0; rt < 2; rt++) {
#pragma unroll
        for (int c = 0; c < 8; c++) {
            int col = c * 16 + l15;
            float bv = bias[col];
#pragma unroll
            for (int i = 0; i < 4; i++) {
                int row = rowBase + wave * 32 + rt * 16 + quad * 4 + i;
                if (row < N) C[(size_t)row * 128 + col] = f2bf(acc[rt][c][i] + bv);
            }
        }
    }
}

// MFMA gemm40: H40[N,64-stride](bf16, cols<40) = A[N,128](bf16) @ Wt3[48][128] + b3.
// Wt3 staged in LDS once; A staged per 32-k step.
__global__ __launch_bounds__(256) void k_gemm40_mfma(const unsigned short* __restrict__ A,
                                                     const unsigned short* __restrict__ Wt3,
                                                     const float* __restrict__ bias,
                                                     unsigned short* __restrict__ C, int N) {
    __shared__ unsigned short As[128 * 40];
    __shared__ unsigned short Bs[48 * 136];  // pad stride 136 shorts (68 dwords)
    const int tid = threadIdx.x;
    const int wave = tid >> 6, lane = tid & 63;
    const int quad = lane >> 4, l15 = lane & 15;
    const int rowBase = blockIdx.x * 128;

    // stage full Wt3 (48 rows x 128 k) once: 768 uint4 chunks
    for (int t = tid; t < 48 * 16; t += 256) {
        int r = t >> 4, kc = t & 15;
        uint4 v = *(const uint4*)&Wt3[r * 128 + kc * 8];
        *(uint4*)&Bs[r * 136 + kc * 8] = v;
    }

    const float4v z = {0.f, 0.f, 0.f, 0.f};
    float4v acc[2][3];
#pragma unroll
    for (int i = 0; i < 2; i++)
#pragma unroll
        for (int j = 0; j < 3; j++) acc[i][j] = z;

    for (int k0 = 0; k0 < 128; k0 += 32) {
#pragma unroll
        for (int i = 0; i < 2; i++) {
            int t = i * 256 + tid;
            int r = t >> 2;
            int kc = t & 3;
            int rg = rowBase + r;
            rg = rg < N ? rg : N - 1;
            uint4 va = *(const uint4*)&A[(size_t)rg * 128 + k0 + kc * 8];
            *(uint4*)&As[r * 40 + kc * 8] = va;
        }
        __syncthreads();

        short8 a0 = *(const short8*)&As[(wave * 32 + l15) * 40 + quad * 8];
        short8 a1 = *(const short8*)&As[(wave * 32 + 16 + l15) * 40 + quad * 8];
#pragma unroll
        for (int c = 0; c < 3; c++) {
            short8 b = *(const short8*)&Bs[(c * 16 + l15) * 136 + k0 + quad * 8];
            acc[0][c] = __builtin_amdgcn_mfma_f32_16x16x32_bf16(a0, b, acc[0][c], 0, 0, 0);
            acc[1][c] = __builtin_amdgcn_mfma_f32_16x16x32_bf16(a1, b, acc[1][c], 0, 0, 0);
        }
        __syncthreads();
    }

#pragma unroll
    for (int rt = 0; rt < 2; rt++) {
#pragma unroll
        for (int c = 0; c < 3; c++) {
            int col = c * 16 + l15;
            if (col < 40) {
                float bv = bias[col];
#pragma unroll
                for (int i = 0; i < 4; i++) {
                    int row = rowBase + wave * 32 + rt * 16 + quad * 4 + i;
                    if (row < N) C[(size_t)row * 64 + col] = f2bf(acc[rt][c][i] + bv);
                }
            }
        }
    }
}

// ---------------------------------------------------------------------------
// Pull aggregation, F=128 bf16 gather; one wave/node; bf16 out (+opt resid)
// ---------------------------------------------------------------------------
__global__ __launch_bounds__(256) void k_agg128(const unsigned short* __restrict__ h,
                                                const int* __restrict__ rowptr,
                                                const int2* __restrict__ perm,
                                                const unsigned short* __restrict__ resid,
                                                unsigned short* __restrict__ out, int N) {
    int node = (blockIdx.x * 256 + threadIdx.x) >> 6;
    if (node >= N) return;
    int lane = threadIdx.x & 63;
    int beg = rowptr[node], end = rowptr[node + 1];
    float ax0 = 0.f, ay0 = 0.f, ax1 = 0.f, ay1 = 0.f;
    int e = beg;
    for (; e + 3 < end; e += 4) {
        int2 p0 = perm[e], p1 = perm[e + 1], p2 = perm[e + 2], p3 = perm[e + 3];
        unsigned int v0 = *(const unsigned int*)&h[(size_t)p0.x * 128 + lane * 2];
        unsigned int v1 = *(const unsigned int*)&h[(size_t)p1.x * 128 + lane * 2];
        unsigned int v2 = *(const unsigned int*)&h[(size_t)p2.x * 128 + lane * 2];
        unsigned int v3 = *(const unsigned int*)&h[(size_t)p3.x * 128 + lane * 2];
        float w0 = __int_as_float(p0.y), w1 = __int_as_float(p1.y);
        float w2 = __int_as_float(p2.y), w3 = __int_as_float(p3.y);
        ax0 = fmaf(bf2f_lo(v0), w0, ax0); ay0 = fmaf(bf2f_hi(v0), w0, ay0);
        ax1 = fmaf(bf2f_lo(v1), w1, ax1); ay1 = fmaf(bf2f_hi(v1), w1, ay1);
        ax0 = fmaf(bf2f_lo(v2), w2, ax0); ay0 = fmaf(bf2f_hi(v2), w2, ay0);
        ax1 = fmaf(bf2f_lo(v3), w3, ax1); ay1 = fmaf(bf2f_hi(v3), w3, ay1);
    }
    for (; e < end; e++) {
        int2 p = perm[e];
        unsigned int v = *(const unsigned int*)&h[(size_t)p.x * 128 + lane * 2];
        float w = __int_as_float(p.y);
        ax0 = fmaf(bf2f_lo(v), w, ax0);
        ay0 = fmaf(bf2f_hi(v), w, ay0);
    }
    float ax = fmaxf(ax0 + ax1, 0.f);
    float ay = fmaxf(ay0 + ay1, 0.f);
    if (resid) {
        unsigned int rv = *(const unsigned int*)&resid[(size_t)node * 128 + lane * 2];
        ax += bf2f_lo(rv);
        ay += bf2f_hi(rv);
    }
    unsigned int o = (unsigned int)f2bf(ax) | ((unsigned int)f2bf(ay) << 16);
    *(unsigned int*)&out[(size_t)node * 128 + lane * 2] = o;
}

// Final layer: gather h40 (bf16, stride 64) + log_softmax fused. fp32 out.
__global__ __launch_bounds__(256) void k_agg40_lsm(const unsigned short* __restrict__ h,
                                                   const int* __restrict__ rowptr,
                                                   const int2* __restrict__ perm,
                                                   float* __restrict__ out, int N) {
    int node = (blockIdx.x * 256 + threadIdx.x) >> 6;
    if (node >= N) return;
    int lane = threadIdx.x & 63;
    int cl = lane < 40 ? lane : 0;
    int beg = rowptr[node], end = rowptr[node + 1];
    float a0 = 0.f, a1 = 0.f;
    int e = beg;
    for (; e + 3 < end; e += 4) {
        int2 p0 = perm[e], p1 = perm[e + 1], p2 = perm[e + 2], p3 = perm[e + 3];
        float v0 = __uint_as_float((unsigned int)h[(size_t)p0.x * 64 + cl] << 16);
        float v1 = __uint_as_float((unsigned int)h[(size_t)p1.x * 64 + cl] << 16);
        float v2 = __uint_as_float((unsigned int)h[(size_t)p2.x * 64 + cl] << 16);
        float v3 = __uint_as_float((unsigned int)h[(size_t)p3.x * 64 + cl] << 16);
        a0 = fmaf(v0, __int_as_float(p0.y), a0);
        a1 = fmaf(v1, __int_as_float(p1.y), a1);
        a0 = fmaf(v2, __int_as_float(p2.y), a0);
        a1 = fmaf(v3, __int_as_float(p3.y), a1);
    }
    for (; e < end; e++) {
        int2 p = perm[e];
        float v = __uint_as_float((unsigned int)h[(size_t)p.x * 64 + cl] << 16);
        a0 = fmaf(v, __int_as_float(p.y), a0);
    }
    float acc = a0 + a1;

    float x = (lane < 40) ? acc : -__builtin_inff();
    float m = x;
#pragma unroll
    for (int off = 32; off > 0; off >>= 1) m = fmaxf(m, __shfl_xor(m, off, 64));
    float ex = (lane < 40) ? expf(x - m) : 0.f;
    float s = ex;
#pragma unroll
    for (int off = 32; off > 0; off >>= 1) s += __shfl_xor(s, off, 64);
    float ls = logf(s);
    if (lane < 40) out[(size_t)node * 40 + lane] = x - m - ls;
}

extern "C" void kernel_launch(void* const* d_in, const int* in_sizes, int n_in,
                              void* d_out, int out_size, void* d_ws, size_t ws_size,
                              hipStream_t stream) {
    const float* x  = (const float*)d_in[0];
    const int*   src = (const int*)d_in[1];
    const int*   tgt = (const int*)d_in[2];
    const float* ew  = (const float*)d_in[3];
    const float* W0 = (const float*)d_in[4];
    const float* b0 = (const float*)d_in[5];
    const float* W1 = (const float*)d_in[6];
    const float* b1 = (const float*)d_in[7];
    const float* W2 = (const float*)d_in[8];
    const float* b2 = (const float*)d_in[9];
    const float* W3 = (const float*)d_in[10];
    const float* b3 = (const float*)d_in[11];

    const int N = in_sizes[0] / 256;
    const int E = in_sizes[1];
    const int NC = (N + 4095) >> 12;  // chunks of 4096 nodes (<=32)

    char* ws = (char*)d_ws;
    size_t off = 0;
    auto alloc = [&](size_t bytes) -> void* {
        void* p = ws + off;
        off = (off + bytes + 255) & ~(size_t)255;
        return p;
    };
    // buf0: Xb (bf16 N*256) ; later reused as XCb (bf16 N*128, L2 agg out)
    char* buf0 = (char*)alloc((size_t)N * 256 * 2);
    unsigned short* Xb  = (unsigned short*)buf0;
    unsigned short* XCb = (unsigned short*)buf0;
    // Hb also hosts the CSR staging arrays (dead before first gemm)
    char* hbuf = (char*)alloc((size_t)N * 128 * 2);
    unsigned short* Hb = (unsigned short*)hbuf;
    int2* st_srcw = (int2*)hbuf;                        // E*8 bytes
    int*  st_tgt  = (int*)(hbuf + (size_t)E * 8);       // E*4 bytes (fits: 19.2MB<25.6MB)
    // XAb aliases H40b (XAb dead after L2 agg)
    char* buf1 = (char*)alloc((size_t)N * 128 * 2);
    unsigned short* XAb  = (unsigned short*)buf1;
    unsigned short* H40b = (unsigned short*)buf1;
    unsigned short* XBb  = (unsigned short*)alloc((size_t)N * 128 * 2);
    int*   deg     = (int*)alloc((size_t)N * 4);
    int*   rowptr  = (int*)alloc((size_t)(N + 1) * 4);
    int*   cursor  = (int*)alloc((size_t)N * 4);
    int*   partial = (int*)alloc(64 * 4);
    int*   chunkCur= (int*)alloc(32 * 32 * 4);  // padded: 1 counter / 128B
    int2*  perm    = (int2*)alloc((size_t)E * 8);
    unsigned short* Wt0 = (unsigned short*)alloc(256 * 128 * 2);
    unsigned short* Wt1 = (unsigned short*)alloc(128 * 128 * 2);
    unsigned short* Wt2 = (unsigned short*)alloc(128 * 128 * 2);
    unsigned short* Wt3 = (unsigned short*)alloc(48 * 128 * 2);
    (void)ws_size;

    const int nChunk = (N + 4095) / 4096;
    float* logits = (float*)d_out;

    // CSR build
    k_zero<<<(N + 255) / 256, 256, 0, stream>>>(deg, N);
    k_hist<<<(E + 255) / 256, 256, 0, stream>>>(tgt, deg, E);
    k_scan1<<<nChunk, 256, 0, stream>>>(deg, partial, N);
    k_scan2<<<1, 64, 0, stream>>>(partial, nChunk);
    k_scan3<<<nChunk, 256, 0, stream>>>(deg, partial, rowptr, cursor, N, E);
    k_chunkinit<<<1, 32, 0, stream>>>(rowptr, chunkCur, NC, N);
    k_bucket<<<(E + 1023) / 1024, 256, 0, stream>>>(src, tgt, ew, chunkCur,
                                                    st_srcw, st_tgt, E);
    k_fill2<<<(E + 255) / 256, 256, 0, stream>>>(st_srcw, st_tgt, cursor, perm, E);

    // dtype prep
    const int nx = N * 256;
    k_cast_bf16<<<(nx / 4 + 255) / 256, 256, 0, stream>>>(x, Xb, nx);
    k_wtrans<<<(256 * 128 + 255) / 256, 256, 0, stream>>>(W0, Wt0, 256, 128);
    k_wtrans<<<(128 * 128 + 255) / 256, 256, 0, stream>>>(W1, Wt1, 128, 128);
    k_wtrans<<<(128 * 128 + 255) / 256, 256, 0, stream>>>(W2, Wt2, 128, 128);
    k_wtrans40<<<(48 * 128 + 255) / 256, 256, 0, stream>>>(W3, Wt3);

    const int gGemm = (N + 127) / 128;
    const int gWave = (N + 3) / 4;

    // L0
    k_gemm_mfma<256><<<gGemm, 256, 0, stream>>>(Xb, Wt0, b0, Hb, N);
    k_agg128<<<gWave, 256, 0, stream>>>(Hb, rowptr, perm, nullptr, XAb, N);
    // L1
    k_gemm_mfma<128><<<gGemm, 256, 0, stream>>>(XAb, Wt1, b1, Hb, N);
    k_agg128<<<gWave, 256, 0, stream>>>(Hb, rowptr, perm, nullptr, XBb, N);
    // L2 (+residual XAb) -> XCb (bf16, overwrites dead Xb)
    k_gemm_mfma<128><<<gGemm, 256, 0, stream>>>(XBb, Wt2, b2, Hb, N);
    k_agg128<<<gWave, 256, 0, stream>>>(Hb, rowptr, perm, XAb, XCb, N);
    // L3
    k_gemm40_mfma<<<gGemm, 256, 0, stream>>>(XCb, Wt3, b3, H40b, N);
    k_agg40_lsm<<<gWave, 256, 0, stream>>>(H40b, rowptr, perm, logits, N);
}

// Round 5
// 667.953 us; speedup vs baseline: 1.9300x; 1.1121x over previous
//
#include <hip/hip_runtime.h>
#include <hip/hip_bf16.h>

// ---------------------------------------------------------------------------
// RESK2 4-layer GCN on MI355X — round 4b (compile fix of r4: macros -> inline fns).
//   CSR: zero -> hist -> scan1 -> scan3(+scan2+chunkinit) -> bucket -> fill2
//   wtrans_all (one kernel for Wt0..Wt3)
//   L0: mfma_gemm<256,f32-A>(x,Wt0,b0)->Hb ; agg128->XAb
//   L1: mfma_gemm<128>(XAb,Wt1,b1)->Hb     ; agg128->XBb
//   L2: mfma_gemm<128>(XBb,Wt2,b2)->Hb     ; agg128+XAb->XCb
//   L3: gemm40_mfma(XCb,Wt3,b3)->H40b      ; agg40+log_softmax -> d_out
// agg128: quarter-wave (16 lanes x 16B) gather -> 4 edges per load instr.
// ---------------------------------------------------------------------------

typedef __attribute__((ext_vector_type(8))) short short8;
typedef __attribute__((ext_vector_type(4))) float float4v;

static __device__ __forceinline__ float bf2f_lo(unsigned int v) {
    return __uint_as_float(v << 16);
}
static __device__ __forceinline__ float bf2f_hi(unsigned int v) {
    return __uint_as_float(v & 0xffff0000u);
}
static __device__ __forceinline__ unsigned short f2bf(float f) {
    unsigned int u = __float_as_uint(f);
    u = (u + 0x7fffu + ((u >> 16) & 1u)) >> 16;  // RNE
    return (unsigned short)u;
}
static __device__ __forceinline__ unsigned int packbf(float a, float b) {
    return (unsigned int)f2bf(a) | ((unsigned int)f2bf(b) << 16);
}

static __device__ __forceinline__ void acc8(float* acc, uint4 v, float wt) {
    acc[0] = fmaf(bf2f_lo(v.x), wt, acc[0]);
    acc[1] = fmaf(bf2f_hi(v.x), wt, acc[1]);
    acc[2] = fmaf(bf2f_lo(v.y), wt, acc[2]);
    acc[3] = fmaf(bf2f_hi(v.y), wt, acc[3]);
    acc[4] = fmaf(bf2f_lo(v.z), wt, acc[4]);
    acc[5] = fmaf(bf2f_hi(v.z), wt, acc[5]);
    acc[6] = fmaf(bf2f_lo(v.w), wt, acc[6]);
    acc[7] = fmaf(bf2f_hi(v.w), wt, acc[7]);
}
static __device__ __forceinline__ void acc4(float* acc, uint2 v, float wt) {
    acc[0] = fmaf(bf2f_lo(v.x), wt, acc[0]);
    acc[1] = fmaf(bf2f_hi(v.x), wt, acc[1]);
    acc[2] = fmaf(bf2f_lo(v.y), wt, acc[2]);
    acc[3] = fmaf(bf2f_hi(v.y), wt, acc[3]);
}

// ------------------------------- CSR build --------------------------------
__global__ __launch_bounds__(256) void k_zero(int* __restrict__ p, int n) {
    int i = blockIdx.x * 256 + threadIdx.x;
    if (i < n) p[i] = 0;
}

__global__ __launch_bounds__(256) void k_hist(const int* __restrict__ tgt,
                                              int* __restrict__ deg, int E) {
    int e = blockIdx.x * 256 + threadIdx.x;
    if (e < E) atomicAdd(&deg[tgt[e]], 1);
}

__global__ __launch_bounds__(256) void k_scan1(const int* __restrict__ deg,
                                               int* __restrict__ partial, int N) {
    __shared__ int sm[256];
    int tid = threadIdx.x;
    int base = blockIdx.x * 4096;
    int s = 0;
    for (int i = tid; i < 4096; i += 256) {
        int idx = base + i;
        s += (idx < N) ? deg[idx] : 0;
    }
    sm[tid] = s;
    __syncthreads();
    for (int off = 128; off > 0; off >>= 1) {
        if (tid < off) sm[tid] += sm[tid + off];
        __syncthreads();
    }
    if (tid == 0) partial[blockIdx.x] = sm[0];
}

// scan3 + (scan2 of partials, redundant per block) + chunkCur init
__global__ __launch_bounds__(256) void k_scan3(const int* __restrict__ deg,
                                               const int* __restrict__ partial,
                                               int* __restrict__ rowptr,
                                               int* __restrict__ cursor,
                                               int* __restrict__ chunkCur,
                                               int N, int E, int nChunk) {
    __shared__ int sm[256];
    __shared__ int pex;
    int tid = threadIdx.x;
    if (tid == 0) {
        int acc = 0;
        for (int i = 0; i < nChunk; i++) {
            if (i == (int)blockIdx.x) pex = acc;
            if (blockIdx.x == 0) chunkCur[i * 32] = acc;
            acc += partial[i];
        }
    }
    int base = blockIdx.x * 4096 + tid * 16;
    int v[16];
    int tot = 0;
#pragma unroll
    for (int j = 0; j < 16; j++) {
        int idx = base + j;
        v[j] = (idx < N) ? deg[idx] : 0;
        tot += v[j];
    }
    sm[tid] = tot;
    __syncthreads();
    for (int off = 1; off < 256; off <<= 1) {
        int t = (tid >= off) ? sm[tid - off] : 0;
        __syncthreads();
        sm[tid] += t;
        __syncthreads();
    }
    int run = pex + sm[tid] - tot;
#pragma unroll
    for (int j = 0; j < 16; j++) {
        int idx = base + j;
        if (idx < N) {
            rowptr[idx] = run;
            cursor[idx] = run;
            run += v[j];
        }
    }
    if (blockIdx.x == 0 && tid == 0) rowptr[N] = E;
}

// Phase A: bucket 1024 edges/block by tgt>>12 into staging
__global__ __launch_bounds__(256) void k_bucket(const int* __restrict__ src,
                                                const int* __restrict__ tgt,
                                                const float* __restrict__ ew,
                                                int* __restrict__ chunkCur,
                                                int2* __restrict__ st_srcw,
                                                int* __restrict__ st_tgt, int E) {
    __shared__ int cnt[32];
    __shared__ int base[32];
    __shared__ int rk[32];
    const int tid = threadIdx.x;
    const int e0 = blockIdx.x * 1024 + tid * 4;

    if (tid < 32) { cnt[tid] = 0; rk[tid] = 0; }
    __syncthreads();

    int t4[4], s4[4], w4[4], c4[4];
    bool full = (e0 + 3 < E);
    if (full) {
        int4 tv = *(const int4*)&tgt[e0];
        int4 sv = *(const int4*)&src[e0];
        float4 wv = *(const float4*)&ew[e0];
        t4[0] = tv.x; t4[1] = tv.y; t4[2] = tv.z; t4[3] = tv.w;
        s4[0] = sv.x; s4[1] = sv.y; s4[2] = sv.z; s4[3] = sv.w;
        w4[0] = __float_as_int(wv.x); w4[1] = __float_as_int(wv.y);
        w4[2] = __float_as_int(wv.z); w4[3] = __float_as_int(wv.w);
    } else {
#pragma unroll
        for (int j = 0; j < 4; j++) {
            int e = e0 + j;
            t4[j] = (e < E) ? tgt[e] : -1;
            s4[j] = (e < E) ? src[e] : 0;
            w4[j] = (e < E) ? __float_as_int(ew[e]) : 0;
        }
    }
#pragma unroll
    for (int j = 0; j < 4; j++) {
        c4[j] = t4[j] >> 12;
        if (t4[j] >= 0) atomicAdd(&cnt[c4[j]], 1);
    }
    __syncthreads();
    if (tid < 32) {
        int c = cnt[tid];
        base[tid] = c ? atomicAdd(&chunkCur[tid * 32], c) : 0;
    }
    __syncthreads();
#pragma unroll
    for (int j = 0; j < 4; j++) {
        if (t4[j] >= 0) {
            int r = atomicAdd(&rk[c4[j]], 1);
            int pos = base[c4[j]] + r;
            st_srcw[pos] = make_int2(s4[j], w4[j]);
            st_tgt[pos] = t4[j];
        }
    }
}

// Phase B: linear sweep; scatter confined to per-chunk L2 windows
__global__ __launch_bounds__(256) void k_fill2(const int2* __restrict__ st_srcw,
                                               const int* __restrict__ st_tgt,
                                               int* __restrict__ cursor,
                                               int2* __restrict__ perm, int E) {
    int e = blockIdx.x * 256 + threadIdx.x;
    if (e < E) {
        int t = st_tgt[e];
        int p = atomicAdd(&cursor[t], 1);
        perm[p] = st_srcw[e];
    }
}

// ----------------------------- weight prep --------------------------------
__global__ __launch_bounds__(256) void k_wtrans_all(
    const float* __restrict__ W0, const float* __restrict__ W1,
    const float* __restrict__ W2, const float* __restrict__ W3,
    unsigned short* __restrict__ Wt0, unsigned short* __restrict__ Wt1,
    unsigned short* __restrict__ Wt2, unsigned short* __restrict__ Wt3) {
    int idx = blockIdx.x * 256 + threadIdx.x;
    if (idx < 32768) {                       // W0: K=256, C=128
        int c = idx >> 8, k = idx & 255;
        Wt0[idx] = f2bf(W0[k * 128 + c]);
    } else if (idx < 49152) {                // W1
        int i = idx - 32768;
        int c = i >> 7, k = i & 127;
        Wt1[i] = f2bf(W1[k * 128 + c]);
    } else if (idx < 65536) {                // W2
        int i = idx - 49152;
        int c = i >> 7, k = i & 127;
        Wt2[i] = f2bf(W2[k * 128 + c]);
    } else if (idx < 71680) {                // W3 -> [48][128]
        int i = idx - 65536;
        int c = i >> 7, k = i & 127;
        Wt3[i] = (c < 40) ? f2bf(W3[k * 40 + c]) : 0;
    }
}

// ---------------------------------------------------------------------------
// MFMA GEMM: C[N,128](bf16) = A[N,K] @ Wt[128][K] + b. 128x128/block.
// AF32: A is fp32 (converted to bf16 during staging), else bf16.
// ---------------------------------------------------------------------------
template <int K, int AF32>
__global__ __launch_bounds__(256) void k_gemm_mfma(const void* __restrict__ Av,
                                                   const unsigned short* __restrict__ Wt,
                                                   const float* __restrict__ bias,
                                                   unsigned short* __restrict__ C, int N) {
    __shared__ unsigned short As[128 * 40];
    __shared__ unsigned short Bs[128 * 40];
    const unsigned short* A16 = (const unsigned short*)Av;
    const float* A32 = (const float*)Av;
    const int tid = threadIdx.x;
    const int wave = tid >> 6, lane = tid & 63;
    const int quad = lane >> 4, l15 = lane & 15;
    const int rowBase = blockIdx.x * 128;

    const float4v z = {0.f, 0.f, 0.f, 0.f};
    float4v acc[2][8];
#pragma unroll
    for (int i = 0; i < 2; i++)
#pragma unroll
        for (int j = 0; j < 8; j++) acc[i][j] = z;

    for (int k0 = 0; k0 < K; k0 += 32) {
#pragma unroll
        for (int i = 0; i < 2; i++) {
            int t = i * 256 + tid;
            int r = t >> 2;
            int kc = t & 3;
            int rg = rowBase + r;
            rg = rg < N ? rg : N - 1;
            uint4 va;
            if (AF32) {
                float4 f0 = *(const float4*)&A32[(size_t)rg * K + k0 + kc * 8];
                float4 f1 = *(const float4*)&A32[(size_t)rg * K + k0 + kc * 8 + 4];
                va.x = packbf(f0.x, f0.y);
                va.y = packbf(f0.z, f0.w);
                va.z = packbf(f1.x, f1.y);
                va.w = packbf(f1.z, f1.w);
            } else {
                va = *(const uint4*)&A16[(size_t)rg * K + k0 + kc * 8];
            }
            *(uint4*)&As[r * 40 + kc * 8] = va;
            uint4 vb = *(const uint4*)&Wt[(size_t)r * K + k0 + kc * 8];
            *(uint4*)&Bs[r * 40 + kc * 8] = vb;
        }
        __syncthreads();

        short8 a0 = *(const short8*)&As[(wave * 32 + l15) * 40 + quad * 8];
        short8 a1 = *(const short8*)&As[(wave * 32 + 16 + l15) * 40 + quad * 8];
#pragma unroll
        for (int c = 0; c < 8; c++) {
            short8 b = *(const short8*)&Bs[(c * 16 + l15) * 40 + quad * 8];
            acc[0][c] = __builtin_amdgcn_mfma_f32_16x16x32_bf16(a0, b, acc[0][c], 0, 0, 0);
            acc[1][c] = __builtin_amdgcn_mfma_f32_16x16x32_bf16(a1, b, acc[1][c], 0, 0, 0);
        }
        __syncthreads();
    }

#pragma unroll
    for (int rt = 0; rt < 2; rt++) {
#pragma unroll
        for (int c = 0; c < 8; c++) {
            int col = c * 16 + l15;
            float bv = bias[col];
#pragma unroll
            for (int i = 0; i < 4; i++) {
                int row = rowBase + wave * 32 + rt * 16 + quad * 4 + i;
                if (row < N) C[(size_t)row * 128 + col] = f2bf(acc[rt][c][i] + bv);
            }
        }
    }
}

// MFMA gemm40: H40[N,64-stride](bf16, cols<40) = A[N,128](bf16) @ Wt3[48][128] + b3.
__global__ __launch_bounds__(256) void k_gemm40_mfma(const unsigned short* __restrict__ A,
                                                     const unsigned short* __restrict__ Wt3,
                                                     const float* __restrict__ bias,
                                                     unsigned short* __restrict__ C, int N) {
    __shared__ unsigned short As[128 * 40];
    __shared__ unsigned short Bs[48 * 136];
    const int tid = threadIdx.x;
    const int wave = tid >> 6, lane = tid & 63;
    const int quad = lane >> 4, l15 = lane & 15;
    const int rowBase = blockIdx.x * 128;

    for (int t = tid; t < 48 * 16; t += 256) {
        int r = t >> 4, kc = t & 15;
        uint4 v = *(const uint4*)&Wt3[r * 128 + kc * 8];
        *(uint4*)&Bs[r * 136 + kc * 8] = v;
    }

    const float4v z = {0.f, 0.f, 0.f, 0.f};
    float4v acc[2][3];
#pragma unroll
    for (int i = 0; i < 2; i++)
#pragma unroll
        for (int j = 0; j < 3; j++) acc[i][j] = z;

    for (int k0 = 0; k0 < 128; k0 += 32) {
#pragma unroll
        for (int i = 0; i < 2; i++) {
            int t = i * 256 + tid;
            int r = t >> 2;
            int kc = t & 3;
            int rg = rowBase + r;
            rg = rg < N ? rg : N - 1;
            uint4 va = *(const uint4*)&A[(size_t)rg * 128 + k0 + kc * 8];
            *(uint4*)&As[r * 40 + kc * 8] = va;
        }
        __syncthreads();

        short8 a0 = *(const short8*)&As[(wave * 32 + l15) * 40 + quad * 8];
        short8 a1 = *(const short8*)&As[(wave * 32 + 16 + l15) * 40 + quad * 8];
#pragma unroll
        for (int c = 0; c < 3; c++) {
            short8 b = *(const short8*)&Bs[(c * 16 + l15) * 136 + k0 + quad * 8];
            acc[0][c] = __builtin_amdgcn_mfma_f32_16x16x32_bf16(a0, b, acc[0][c], 0, 0, 0);
            acc[1][c] = __builtin_amdgcn_mfma_f32_16x16x32_bf16(a1, b, acc[1][c], 0, 0, 0);
        }
        __syncthreads();
    }

#pragma unroll
    for (int rt = 0; rt < 2; rt++) {
#pragma unroll
        for (int c = 0; c < 3; c++) {
            int col = c * 16 + l15;
            if (col < 40) {
                float bv = bias[col];
#pragma unroll
                for (int i = 0; i < 4; i++) {
                    int row = rowBase + wave * 32 + rt * 16 + quad * 4 + i;
                    if (row < N) C[(size_t)row * 64 + col] = f2bf(acc[rt][c][i] + bv);
                }
            }
        }
    }
}

// ---------------------------------------------------------------------------
// Pull aggregation F=128: one wave/node, quarter-wave per edge.
// Group g=lane>>4 handles edge slot g; lane l=lane&15 holds features 8l..8l+7.
// ---------------------------------------------------------------------------
__global__ __launch_bounds__(256) void k_agg128(const unsigned short* __restrict__ h,
                                                const int* __restrict__ rowptr,
                                                const int2* __restrict__ perm,
                                                const unsigned short* __restrict__ resid,
                                                unsigned short* __restrict__ out, int N) {
    int node = (blockIdx.x * 256 + threadIdx.x) >> 6;
    if (node >= N) return;
    const int lane = threadIdx.x & 63;
    const int g = lane >> 4, l = lane & 15;
    const int beg = rowptr[node], end = rowptr[node + 1];
    const int last = end - 1;

    float acc[8] = {};
    for (int base = beg; base < end; base += 16) {
        int e0 = base + g, e1 = base + 4 + g, e2 = base + 8 + g, e3 = base + 12 + g;
        int2 p0 = perm[e0 <= last ? e0 : last];
        int2 p1 = perm[e1 <= last ? e1 : last];
        int2 p2 = perm[e2 <= last ? e2 : last];
        int2 p3 = perm[e3 <= last ? e3 : last];
        uint4 a0 = *(const uint4*)&h[(size_t)p0.x * 128 + l * 8];
        uint4 a1 = *(const uint4*)&h[(size_t)p1.x * 128 + l * 8];
        uint4 a2 = *(const uint4*)&h[(size_t)p2.x * 128 + l * 8];
        uint4 a3 = *(const uint4*)&h[(size_t)p3.x * 128 + l * 8];
        float w0 = e0 <= last ? __int_as_float(p0.y) : 0.f;
        float w1 = e1 <= last ? __int_as_float(p1.y) : 0.f;
        float w2 = e2 <= last ? __int_as_float(p2.y) : 0.f;
        float w3 = e3 <= last ? __int_as_float(p3.y) : 0.f;
        acc8(acc, a0, w0);
        acc8(acc, a1, w1);
        acc8(acc, a2, w2);
        acc8(acc, a3, w3);
    }

    // combine across 4 quarter-groups
#pragma unroll
    for (int i = 0; i < 8; i++) {
        acc[i] += __shfl_xor(acc[i], 16);
        acc[i] += __shfl_xor(acc[i], 32);
    }

    if (g == 0) {
#pragma unroll
        for (int i = 0; i < 8; i++) acc[i] = fmaxf(acc[i], 0.f);
        if (resid) {
            uint4 rv = *(const uint4*)&resid[(size_t)node * 128 + l * 8];
            acc[0] += bf2f_lo(rv.x); acc[1] += bf2f_hi(rv.x);
            acc[2] += bf2f_lo(rv.y); acc[3] += bf2f_hi(rv.y);
            acc[4] += bf2f_lo(rv.z); acc[5] += bf2f_hi(rv.z);
            acc[6] += bf2f_lo(rv.w); acc[7] += bf2f_hi(rv.w);
        }
        uint4 o;
        o.x = packbf(acc[0], acc[1]);
        o.y = packbf(acc[2], acc[3]);
        o.z = packbf(acc[4], acc[5]);
        o.w = packbf(acc[6], acc[7]);
        *(uint4*)&out[(size_t)node * 128 + l * 8] = o;
    }
}

// ---------------------------------------------------------------------------
// Final layer: F=40 gather (h stride 64 shorts), half-wave per edge,
// fused log_softmax, float4 store. l=lane&31 holds features 4l..4l+3 (l<10).
// ---------------------------------------------------------------------------
__global__ __launch_bounds__(256) void k_agg40_lsm(const unsigned short* __restrict__ h,
                                                   const int* __restrict__ rowptr,
                                                   const int2* __restrict__ perm,
                                                   float* __restrict__ out, int N) {
    int node = (blockIdx.x * 256 + threadIdx.x) >> 6;
    if (node >= N) return;
    const int lane = threadIdx.x & 63;
    const int hh = lane >> 5, l = lane & 31;
    const int beg = rowptr[node], end = rowptr[node + 1];
    const int last = end - 1;

    float acc[4] = {};
    for (int base = beg; base < end; base += 8) {
        int e0 = base + hh, e1 = base + 2 + hh, e2 = base + 4 + hh, e3 = base + 6 + hh;
        int2 p0 = perm[e0 <= last ? e0 : last];
        int2 p1 = perm[e1 <= last ? e1 : last];
        int2 p2 = perm[e2 <= last ? e2 : last];
        int2 p3 = perm[e3 <= last ? e3 : last];
        uint2 a0 = *(const uint2*)&h[(size_t)p0.x * 64 + l * 4];
        uint2 a1 = *(const uint2*)&h[(size_t)p1.x * 64 + l * 4];
        uint2 a2 = *(const uint2*)&h[(size_t)p2.x * 64 + l * 4];
        uint2 a3 = *(const uint2*)&h[(size_t)p3.x * 64 + l * 4];
        float w0 = e0 <= last ? __int_as_float(p0.y) : 0.f;
        float w1 = e1 <= last ? __int_as_float(p1.y) : 0.f;
        float w2 = e2 <= last ? __int_as_float(p2.y) : 0.f;
        float w3 = e3 <= last ? __int_as_float(p3.y) : 0.f;
        acc4(acc, a0, w0);
        acc4(acc, a1, w1);
        acc4(acc, a2, w2);
        acc4(acc, a3, w3);
    }
#pragma unroll
    for (int i = 0; i < 4; i++) acc[i] += __shfl_xor(acc[i], 32);

    // log_softmax over 40 values held by lanes (l<10) x 4
    bool vf = l < 10;
    float m = vf ? fmaxf(fmaxf(acc[0], acc[1]), fmaxf(acc[2], acc[3]))
                 : -__builtin_inff();
#pragma unroll
    for (int off = 1; off < 64; off <<= 1) m = fmaxf(m, __shfl_xor(m, off));
    float s = 0.f;
    if (lane < 10)
        s = expf(acc[0] - m) + expf(acc[1] - m) + expf(acc[2] - m) + expf(acc[3] - m);
#pragma unroll
    for (int off = 1; off < 64; off <<= 1) s += __shfl_xor(s, off);
    float ls = m + logf(s);
    if (lane < 10) {
        float4 o = make_float4(acc[0] - ls, acc[1] - ls, acc[2] - ls, acc[3] - ls);
        *(float4*)&out[(size_t)node * 40 + lane * 4] = o;
    }
}

extern "C" void kernel_launch(void* const* d_in, const int* in_sizes, int n_in,
                              void* d_out, int out_size, void* d_ws, size_t ws_size,
                              hipStream_t stream) {
    const float* x  = (const float*)d_in[0];
    const int*   src = (const int*)d_in[1];
    const int*   tgt = (const int*)d_in[2];
    const float* ew  = (const float*)d_in[3];
    const float* W0 = (const float*)d_in[4];
    const float* b0 = (const float*)d_in[5];
    const float* W1 = (const float*)d_in[6];
    const float* b1 = (const float*)d_in[7];
    const float* W2 = (const float*)d_in[8];
    const float* b2 = (const float*)d_in[9];
    const float* W3 = (const float*)d_in[10];
    const float* b3 = (const float*)d_in[11];

    const int N = in_sizes[0] / 256;
    const int E = in_sizes[1];
    const int nChunk = (N + 4095) >> 12;

    char* ws = (char*)d_ws;
    size_t off = 0;
    auto alloc = [&](size_t bytes) -> void* {
        void* p = ws + off;
        off = (off + bytes + 255) & ~(size_t)255;
        return p;
    };
    unsigned short* XCb = (unsigned short*)alloc((size_t)N * 128 * 2);
    // Hb also hosts the CSR staging arrays (dead before first gemm)
    char* hbuf = (char*)alloc((size_t)E * 12 > (size_t)N * 128 * 2 ? (size_t)E * 12
                                                                   : (size_t)N * 128 * 2);
    unsigned short* Hb = (unsigned short*)hbuf;
    int2* st_srcw = (int2*)hbuf;                   // E*8 bytes
    int*  st_tgt  = (int*)(hbuf + (size_t)E * 8);  // E*4 bytes
    // XAb aliases H40b (XAb dead after L2 agg)
    char* buf1 = (char*)alloc((size_t)N * 128 * 2);
    unsigned short* XAb  = (unsigned short*)buf1;
    unsigned short* H40b = (unsigned short*)buf1;
    unsigned short* XBb  = (unsigned short*)alloc((size_t)N * 128 * 2);
    int*   deg     = (int*)alloc((size_t)N * 4);
    int*   rowptr  = (int*)alloc((size_t)(N + 1) * 4);
    int*   cursor  = (int*)alloc((size_t)N * 4);
    int*   partial = (int*)alloc(64 * 4);
    int*   chunkCur= (int*)alloc(32 * 32 * 4);
    int2*  perm    = (int2*)alloc((size_t)E * 8);
    unsigned short* Wt0 = (unsigned short*)alloc(256 * 128 * 2);
    unsigned short* Wt1 = (unsigned short*)alloc(128 * 128 * 2);
    unsigned short* Wt2 = (unsigned short*)alloc(128 * 128 * 2);
    unsigned short* Wt3 = (unsigned short*)alloc(48 * 128 * 2);
    (void)ws_size;

    float* logits = (float*)d_out;

    // CSR build
    k_zero<<<(N + 255) / 256, 256, 0, stream>>>(deg, N);
    k_hist<<<(E + 255) / 256, 256, 0, stream>>>(tgt, deg, E);
    k_scan1<<<nChunk, 256, 0, stream>>>(deg, partial, N);
    k_scan3<<<nChunk, 256, 0, stream>>>(deg, partial, rowptr, cursor, chunkCur,
                                        N, E, nChunk);
    k_bucket<<<(E + 1023) / 1024, 256, 0, stream>>>(src, tgt, ew, chunkCur,
                                                    st_srcw, st_tgt, E);
    k_fill2<<<(E + 255) / 256, 256, 0, stream>>>(st_srcw, st_tgt, cursor, perm, E);

    // weight prep (one kernel)
    k_wtrans_all<<<(71680 + 255) / 256, 256, 0, stream>>>(W0, W1, W2, W3,
                                                          Wt0, Wt1, Wt2, Wt3);

    const int gGemm = (N + 127) / 128;
    const int gWave = (N + 3) / 4;

    // L0 (reads fp32 x directly)
    k_gemm_mfma<256, 1><<<gGemm, 256, 0, stream>>>(x, Wt0, b0, Hb, N);
    k_agg128<<<gWave, 256, 0, stream>>>(Hb, rowptr, perm, nullptr, XAb, N);
    // L1
    k_gemm_mfma<128, 0><<<gGemm, 256, 0, stream>>>(XAb, Wt1, b1, Hb, N);
    k_agg128<<<gWave, 256, 0, stream>>>(Hb, rowptr, perm, nullptr, XBb, N);
    // L2 (+residual XAb) -> XCb
    k_gemm_mfma<128, 0><<<gGemm, 256, 0, stream>>>(XBb, Wt2, b2, Hb, N);
    k_agg128<<<gWave, 256, 0, stream>>>(Hb, rowptr, perm, XAb, XCb, N);
    // L3
    k_gemm40_mfma<<<gGemm, 256, 0, stream>>>(XCb, Wt3, b3, H40b, N);
    k_agg40_lsm<<<gWave, 256, 0, stream>>>(H40b, rowptr, perm, logits, N);
}

// Round 6
// 544.661 us; speedup vs baseline: 2.3668x; 1.2264x over previous
//
#include <hip/hip_runtime.h>
#include <hip/hip_bf16.h>

// ---------------------------------------------------------------------------
// RESK2 4-layer GCN on MI355X — round 6.
// CSR rebuild: wtrans(+zero) -> count (bucket histogram, 256-node buckets)
//   -> scanB (bucket prefix) -> bucket (dense staging runs, 1B local tgt)
//   -> fill2 (1 block per bucket: local hist+scan -> rowptr, LDS sort ->
//             coalesced perm stream; single-writer = no cross-XCD line bounce)
// Layers unchanged from r4b (MFMA gemms, quarter-wave pull agg).
// ---------------------------------------------------------------------------

typedef __attribute__((ext_vector_type(8))) short short8;
typedef __attribute__((ext_vector_type(4))) float float4v;

#define SC_SHIFT 8              // 256 nodes per sub-chunk
#define SC_NODES 256
#define FILL_CAP 6144           // LDS edge capacity in fill2 (mean ~4096)

static __device__ __forceinline__ float bf2f_lo(unsigned int v) {
    return __uint_as_float(v << 16);
}
static __device__ __forceinline__ float bf2f_hi(unsigned int v) {
    return __uint_as_float(v & 0xffff0000u);
}
static __device__ __forceinline__ unsigned short f2bf(float f) {
    unsigned int u = __float_as_uint(f);
    u = (u + 0x7fffu + ((u >> 16) & 1u)) >> 16;  // RNE
    return (unsigned short)u;
}
static __device__ __forceinline__ unsigned int packbf(float a, float b) {
    return (unsigned int)f2bf(a) | ((unsigned int)f2bf(b) << 16);
}

static __device__ __forceinline__ void acc8(float* acc, uint4 v, float wt) {
    acc[0] = fmaf(bf2f_lo(v.x), wt, acc[0]);
    acc[1] = fmaf(bf2f_hi(v.x), wt, acc[1]);
    acc[2] = fmaf(bf2f_lo(v.y), wt, acc[2]);
    acc[3] = fmaf(bf2f_hi(v.y), wt, acc[3]);
    acc[4] = fmaf(bf2f_lo(v.z), wt, acc[4]);
    acc[5] = fmaf(bf2f_hi(v.z), wt, acc[5]);
    acc[6] = fmaf(bf2f_lo(v.w), wt, acc[6]);
    acc[7] = fmaf(bf2f_hi(v.w), wt, acc[7]);
}
static __device__ __forceinline__ void acc4(float* acc, uint2 v, float wt) {
    acc[0] = fmaf(bf2f_lo(v.x), wt, acc[0]);
    acc[1] = fmaf(bf2f_hi(v.x), wt, acc[1]);
    acc[2] = fmaf(bf2f_lo(v.y), wt, acc[2]);
    acc[3] = fmaf(bf2f_hi(v.y), wt, acc[3]);
}

// --------------------- CSR stage 1: bucket histogram -----------------------
// 256 thr x 16 edges = 4096 edges/block. LDS hist over sub-chunks, then one
// global atomicAdd per non-empty bucket per block.
__global__ __launch_bounds__(256) void k_count(const int* __restrict__ tgt,
                                               int* __restrict__ chunkTot,
                                               int E, int NSC) {
    __shared__ int hist[512];
    const int tid = threadIdx.x;
    hist[tid] = 0;
    hist[tid + 256] = 0;
    __syncthreads();
#pragma unroll
    for (int r = 0; r < 4; r++) {
        int e = blockIdx.x * 4096 + r * 1024 + tid * 4;
        if (e + 3 < E) {
            int4 tv = *(const int4*)&tgt[e];
            atomicAdd(&hist[tv.x >> SC_SHIFT], 1);
            atomicAdd(&hist[tv.y >> SC_SHIFT], 1);
            atomicAdd(&hist[tv.z >> SC_SHIFT], 1);
            atomicAdd(&hist[tv.w >> SC_SHIFT], 1);
        } else {
            for (int j = 0; j < 4; j++)
                if (e + j < E) atomicAdd(&hist[tgt[e + j] >> SC_SHIFT], 1);
        }
    }
    __syncthreads();
    for (int i = tid; i < NSC; i += 256) {
        int c = hist[i];
        if (c) atomicAdd(&chunkTot[i], c);
    }
}

// --------------------- CSR stage 2: bucket prefix scan ---------------------
// single block, 512 threads; writes chunkStart[0..NSC] and padded chunkCur.
__global__ __launch_bounds__(512) void k_scanB(const int* __restrict__ chunkTot,
                                               int* __restrict__ chunkStart,
                                               int* __restrict__ chunkCur,
                                               int E, int NSC) {
    __shared__ int sm[512];
    const int tid = threadIdx.x;
    int v = (tid < NSC) ? chunkTot[tid] : 0;
    sm[tid] = v;
    __syncthreads();
    for (int off = 1; off < 512; off <<= 1) {
        int t = (tid >= off) ? sm[tid - off] : 0;
        __syncthreads();
        sm[tid] += t;
        __syncthreads();
    }
    int excl = sm[tid] - v;
    if (tid < NSC) {
        chunkStart[tid] = excl;
        chunkCur[tid * 32] = excl;
    }
    if (tid == 0) chunkStart[NSC] = E;
}

// --------------------- CSR stage 3: bucket into staging --------------------
// 512 thr x 16 edges = 8192 edges/block; dense runs (~21 edges) per bucket.
__global__ __launch_bounds__(512) void k_bucket(const int* __restrict__ src,
                                                const int* __restrict__ tgt,
                                                const float* __restrict__ ew,
                                                int* __restrict__ chunkCur,
                                                int2* __restrict__ st_srcw,
                                                unsigned char* __restrict__ st_t8,
                                                int E) {
    __shared__ int cnt[512];
    __shared__ int rk[512];
    __shared__ int bbase[512];
    const int tid = threadIdx.x;
    cnt[tid] = 0;
    rk[tid] = 0;
    __syncthreads();

    int t16[16], s16[16], w16[16];
#pragma unroll
    for (int r = 0; r < 4; r++) {
        int e = blockIdx.x * 8192 + r * 2048 + tid * 4;
        if (e + 3 < E) {
            int4 tv = *(const int4*)&tgt[e];
            int4 sv = *(const int4*)&src[e];
            float4 wv = *(const float4*)&ew[e];
            t16[r * 4 + 0] = tv.x; t16[r * 4 + 1] = tv.y;
            t16[r * 4 + 2] = tv.z; t16[r * 4 + 3] = tv.w;
            s16[r * 4 + 0] = sv.x; s16[r * 4 + 1] = sv.y;
            s16[r * 4 + 2] = sv.z; s16[r * 4 + 3] = sv.w;
            w16[r * 4 + 0] = __float_as_int(wv.x);
            w16[r * 4 + 1] = __float_as_int(wv.y);
            w16[r * 4 + 2] = __float_as_int(wv.z);
            w16[r * 4 + 3] = __float_as_int(wv.w);
        } else {
            for (int j = 0; j < 4; j++) {
                int ee = e + j;
                t16[r * 4 + j] = (ee < E) ? tgt[ee] : -1;
                s16[r * 4 + j] = (ee < E) ? src[ee] : 0;
                w16[r * 4 + j] = (ee < E) ? __float_as_int(ew[ee]) : 0;
            }
        }
    }
#pragma unroll
    for (int j = 0; j < 16; j++)
        if (t16[j] >= 0) atomicAdd(&cnt[t16[j] >> SC_SHIFT], 1);
    __syncthreads();
    {
        int c = cnt[tid];
        bbase[tid] = c ? atomicAdd(&chunkCur[tid * 32], c) : 0;
    }
    __syncthreads();
#pragma unroll
    for (int j = 0; j < 16; j++) {
        if (t16[j] >= 0) {
            int c = t16[j] >> SC_SHIFT;
            int pos = bbase[c] + atomicAdd(&rk[c], 1);
            st_srcw[pos] = make_int2(s16[j], w16[j]);
            st_t8[pos] = (unsigned char)(t16[j] & (SC_NODES - 1));
        }
    }
}

// --------------------- CSR stage 4: per-bucket sort ------------------------
// One block per sub-chunk (single writer -> no cross-XCD line bouncing).
// Produces rowptr for its nodes and perm (coalesced stream via LDS).
__global__ __launch_bounds__(256) void k_fill2(const int2* __restrict__ st_srcw,
                                               const unsigned char* __restrict__ st_t8,
                                               const int* __restrict__ chunkStart,
                                               int* __restrict__ rowptr,
                                               int2* __restrict__ perm,
                                               int N, int E, int NSC) {
    __shared__ int lhist[SC_NODES];
    __shared__ int lcur[SC_NODES];
    __shared__ int2 ledge[FILL_CAP];
    const int tid = threadIdx.x;
    const int b = blockIdx.x;
    const int n0 = b << SC_SHIFT;
    const int nlocal = min(SC_NODES, N - n0);
    const int sstart = chunkStart[b];
    const int send = chunkStart[b + 1];
    const int cnt = send - sstart;

    lhist[tid] = 0;
    __syncthreads();
    for (int e = sstart + tid; e < send; e += 256)
        atomicAdd(&lhist[st_t8[e]], 1);
    __syncthreads();
    // exclusive scan over 256
    int v = lhist[tid];
    int s = v;
    __syncthreads();
    lhist[tid] = s;
    __syncthreads();
    for (int off = 1; off < 256; off <<= 1) {
        int t = (tid >= off) ? lhist[tid - off] : 0;
        __syncthreads();
        lhist[tid] += t;
        __syncthreads();
    }
    int excl = lhist[tid] - v;
    if (tid < nlocal) rowptr[n0 + tid] = sstart + excl;
    if (b == NSC - 1 && tid == 0) rowptr[N] = E;
    lcur[tid] = excl;
    __syncthreads();

    if (cnt <= FILL_CAP) {
        for (int e = sstart + tid; e < send; e += 256) {
            int lt = st_t8[e];
            int pos = atomicAdd(&lcur[lt], 1);
            ledge[pos] = st_srcw[e];
        }
        __syncthreads();
        for (int i = tid; i < cnt; i += 256) perm[sstart + i] = ledge[i];
    } else {
        // fallback: scatter directly (still single-writer block, correct)
        for (int e = sstart + tid; e < send; e += 256) {
            int lt = st_t8[e];
            int pos = atomicAdd(&lcur[lt], 1);
            perm[sstart + pos] = st_srcw[e];
        }
    }
}

// ----------------------------- weight prep --------------------------------
// Also zeroes chunkTot (runs first).
__global__ __launch_bounds__(256) void k_wtrans_all(
    const float* __restrict__ W0, const float* __restrict__ W1,
    const float* __restrict__ W2, const float* __restrict__ W3,
    unsigned short* __restrict__ Wt0, unsigned short* __restrict__ Wt1,
    unsigned short* __restrict__ Wt2, unsigned short* __restrict__ Wt3,
    int* __restrict__ chunkTot) {
    int idx = blockIdx.x * 256 + threadIdx.x;
    if (idx < 512) chunkTot[idx] = 0;
    if (idx < 32768) {                       // W0: K=256, C=128
        int c = idx >> 8, k = idx & 255;
        Wt0[idx] = f2bf(W0[k * 128 + c]);
    } else if (idx < 49152) {                // W1
        int i = idx - 32768;
        int c = i >> 7, k = i & 127;
        Wt1[i] = f2bf(W1[k * 128 + c]);
    } else if (idx < 65536) {                // W2
        int i = idx - 49152;
        int c = i >> 7, k = i & 127;
        Wt2[i] = f2bf(W2[k * 128 + c]);
    } else if (idx < 71680) {                // W3 -> [48][128]
        int i = idx - 65536;
        int c = i >> 7, k = i & 127;
        Wt3[i] = (c < 40) ? f2bf(W3[k * 40 + c]) : 0;
    }
}

// ---------------------------------------------------------------------------
// MFMA GEMM: C[N,128](bf16) = A[N,K] @ Wt[128][K] + b. 128x128/block.
// AF32: A is fp32 (converted to bf16 during staging), else bf16.
// ---------------------------------------------------------------------------
template <int K, int AF32>
__global__ __launch_bounds__(256) void k_gemm_mfma(const void* __restrict__ Av,
                                                   const unsigned short* __restrict__ Wt,
                                                   const float* __restrict__ bias,
                                                   unsigned short* __restrict__ C, int N) {
    __shared__ unsigned short As[128 * 40];
    __shared__ unsigned short Bs[128 * 40];
    const unsigned short* A16 = (const unsigned short*)Av;
    const float* A32 = (const float*)Av;
    const int tid = threadIdx.x;
    const int wave = tid >> 6, lane = tid & 63;
    const int quad = lane >> 4, l15 = lane & 15;
    const int rowBase = blockIdx.x * 128;

    const float4v z = {0.f, 0.f, 0.f, 0.f};
    float4v acc[2][8];
#pragma unroll
    for (int i = 0; i < 2; i++)
#pragma unroll
        for (int j = 0; j < 8; j++) acc[i][j] = z;

    for (int k0 = 0; k0 < K; k0 += 32) {
#pragma unroll
        for (int i = 0; i < 2; i++) {
            int t = i * 256 + tid;
            int r = t >> 2;
            int kc = t & 3;
            int rg = rowBase + r;
            rg = rg < N ? rg : N - 1;
            uint4 va;
            if (AF32) {
                float4 f0 = *(const float4*)&A32[(size_t)rg * K + k0 + kc * 8];
                float4 f1 = *(const float4*)&A32[(size_t)rg * K + k0 + kc * 8 + 4];
                va.x = packbf(f0.x, f0.y);
                va.y = packbf(f0.z, f0.w);
                va.z = packbf(f1.x, f1.y);
                va.w = packbf(f1.z, f1.w);
            } else {
                va = *(const uint4*)&A16[(size_t)rg * K + k0 + kc * 8];
            }
            *(uint4*)&As[r * 40 + kc * 8] = va;
            uint4 vb = *(const uint4*)&Wt[(size_t)r * K + k0 + kc * 8];
            *(uint4*)&Bs[r * 40 + kc * 8] = vb;
        }
        __syncthreads();

        short8 a0 = *(const short8*)&As[(wave * 32 + l15) * 40 + quad * 8];
        short8 a1 = *(const short8*)&As[(wave * 32 + 16 + l15) * 40 + quad * 8];
#pragma unroll
        for (int c = 0; c < 8; c++) {
            short8 b = *(const short8*)&Bs[(c * 16 + l15) * 40 + quad * 8];
            acc[0][c] = __builtin_amdgcn_mfma_f32_16x16x32_bf16(a0, b, acc[0][c], 0, 0, 0);
            acc[1][c] = __builtin_amdgcn_mfma_f32_16x16x32_bf16(a1, b, acc[1][c], 0, 0, 0);
        }
        __syncthreads();
    }

#pragma unroll
    for (int rt = 0; rt < 2; rt++) {
#pragma unroll
        for (int c = 0; c < 8; c++) {
            int col = c * 16 + l15;
            float bv = bias[col];
#pragma unroll
            for (int i = 0; i < 4; i++) {
                int row = rowBase + wave * 32 + rt * 16 + quad * 4 + i;
                if (row < N) C[(size_t)row * 128 + col] = f2bf(acc[rt][c][i] + bv);
            }
        }
    }
}

// MFMA gemm40: H40[N,64-stride](bf16, cols<40) = A[N,128](bf16) @ Wt3[48][128] + b3.
__global__ __launch_bounds__(256) void k_gemm40_mfma(const unsigned short* __restrict__ A,
                                                     const unsigned short* __restrict__ Wt3,
                                                     const float* __restrict__ bias,
                                                     unsigned short* __restrict__ C, int N) {
    __shared__ unsigned short As[128 * 40];
    __shared__ unsigned short Bs[48 * 136];
    const int tid = threadIdx.x;
    const int wave = tid >> 6, lane = tid & 63;
    const int quad = lane >> 4, l15 = lane & 15;
    const int rowBase = blockIdx.x * 128;

    for (int t = tid; t < 48 * 16; t += 256) {
        int r = t >> 4, kc = t & 15;
        uint4 v = *(const uint4*)&Wt3[r * 128 + kc * 8];
        *(uint4*)&Bs[r * 136 + kc * 8] = v;
    }

    const float4v z = {0.f, 0.f, 0.f, 0.f};
    float4v acc[2][3];
#pragma unroll
    for (int i = 0; i < 2; i++)
#pragma unroll
        for (int j = 0; j < 3; j++) acc[i][j] = z;

    for (int k0 = 0; k0 < 128; k0 += 32) {
#pragma unroll
        for (int i = 0; i < 2; i++) {
            int t = i * 256 + tid;
            int r = t >> 2;
            int kc = t & 3;
            int rg = rowBase + r;
            rg = rg < N ? rg : N - 1;
            uint4 va = *(const uint4*)&A[(size_t)rg * 128 + k0 + kc * 8];
            *(uint4*)&As[r * 40 + kc * 8] = va;
        }
        __syncthreads();

        short8 a0 = *(const short8*)&As[(wave * 32 + l15) * 40 + quad * 8];
        short8 a1 = *(const short8*)&As[(wave * 32 + 16 + l15) * 40 + quad * 8];
#pragma unroll
        for (int c = 0; c < 3; c++) {
            short8 b = *(const short8*)&Bs[(c * 16 + l15) * 136 + k0 + quad * 8];
            acc[0][c] = __builtin_amdgcn_mfma_f32_16x16x32_bf16(a0, b, acc[0][c], 0, 0, 0);
            acc[1][c] = __builtin_amdgcn_mfma_f32_16x16x32_bf16(a1, b, acc[1][c], 0, 0, 0);
        }
        __syncthreads();
    }

#pragma unroll
    for (int rt = 0; rt < 2; rt++) {
#pragma unroll
        for (int c = 0; c < 3; c++) {
            int col = c * 16 + l15;
            if (col < 40) {
                float bv = bias[col];
#pragma unroll
                for (int i = 0; i < 4; i++) {
                    int row = rowBase + wave * 32 + rt * 16 + quad * 4 + i;
                    if (row < N) C[(size_t)row * 64 + col] = f2bf(acc[rt][c][i] + bv);
                }
            }
        }
    }
}

// ---------------------------------------------------------------------------
// Pull aggregation F=128: one wave/node, quarter-wave per edge.
// Group g=lane>>4 handles edge slot g; lane l=lane&15 holds features 8l..8l+7.
// ---------------------------------------------------------------------------
__global__ __launch_bounds__(256) void k_agg128(const unsigned short* __restrict__ h,
                                                const int* __restrict__ rowptr,
                                                const int2* __restrict__ perm,
                                                const unsigned short* __restrict__ resid,
                                                unsigned short* __restrict__ out, int N) {
    int node = (blockIdx.x * 256 + threadIdx.x) >> 6;
    if (node >= N) return;
    const int lane = threadIdx.x & 63;
    const int g = lane >> 4, l = lane & 15;
    const int beg = rowptr[node], end = rowptr[node + 1];
    const int last = end - 1;

    float acc[8] = {};
    for (int base = beg; base < end; base += 16) {
        int e0 = base + g, e1 = base + 4 + g, e2 = base + 8 + g, e3 = base + 12 + g;
        int2 p0 = perm[e0 <= last ? e0 : last];
        int2 p1 = perm[e1 <= last ? e1 : last];
        int2 p2 = perm[e2 <= last ? e2 : last];
        int2 p3 = perm[e3 <= last ? e3 : last];
        uint4 a0 = *(const uint4*)&h[(size_t)p0.x * 128 + l * 8];
        uint4 a1 = *(const uint4*)&h[(size_t)p1.x * 128 + l * 8];
        uint4 a2 = *(const uint4*)&h[(size_t)p2.x * 128 + l * 8];
        uint4 a3 = *(const uint4*)&h[(size_t)p3.x * 128 + l * 8];
        float w0 = e0 <= last ? __int_as_float(p0.y) : 0.f;
        float w1 = e1 <= last ? __int_as_float(p1.y) : 0.f;
        float w2 = e2 <= last ? __int_as_float(p2.y) : 0.f;
        float w3 = e3 <= last ? __int_as_float(p3.y) : 0.f;
        acc8(acc, a0, w0);
        acc8(acc, a1, w1);
        acc8(acc, a2, w2);
        acc8(acc, a3, w3);
    }

#pragma unroll
    for (int i = 0; i < 8; i++) {
        acc[i] += __shfl_xor(acc[i], 16);
        acc[i] += __shfl_xor(acc[i], 32);
    }

    if (g == 0) {
#pragma unroll
        for (int i = 0; i < 8; i++) acc[i] = fmaxf(acc[i], 0.f);
        if (resid) {
            uint4 rv = *(const uint4*)&resid[(size_t)node * 128 + l * 8];
            acc[0] += bf2f_lo(rv.x); acc[1] += bf2f_hi(rv.x);
            acc[2] += bf2f_lo(rv.y); acc[3] += bf2f_hi(rv.y);
            acc[4] += bf2f_lo(rv.z); acc[5] += bf2f_hi(rv.z);
            acc[6] += bf2f_lo(rv.w); acc[7] += bf2f_hi(rv.w);
        }
        uint4 o;
        o.x = packbf(acc[0], acc[1]);
        o.y = packbf(acc[2], acc[3]);
        o.z = packbf(acc[4], acc[5]);
        o.w = packbf(acc[6], acc[7]);
        *(uint4*)&out[(size_t)node * 128 + l * 8] = o;
    }
}

// ---------------------------------------------------------------------------
// Final layer: F=40 gather (h stride 64 shorts), half-wave per edge,
// fused log_softmax, float4 store. l=lane&31 holds features 4l..4l+3 (l<10).
// ---------------------------------------------------------------------------
__global__ __launch_bounds__(256) void k_agg40_lsm(const unsigned short* __restrict__ h,
                                                   const int* __restrict__ rowptr,
                                                   const int2* __restrict__ perm,
                                                   float* __restrict__ out, int N) {
    int node = (blockIdx.x * 256 + threadIdx.x) >> 6;
    if (node >= N) return;
    const int lane = threadIdx.x & 63;
    const int hh = lane >> 5, l = lane & 31;
    const int beg = rowptr[node], end = rowptr[node + 1];
    const int last = end - 1;

    float acc[4] = {};
    for (int base = beg; base < end; base += 8) {
        int e0 = base + hh, e1 = base + 2 + hh, e2 = base + 4 + hh, e3 = base + 6 + hh;
        int2 p0 = perm[e0 <= last ? e0 : last];
        int2 p1 = perm[e1 <= last ? e1 : last];
        int2 p2 = perm[e2 <= last ? e2 : last];
        int2 p3 = perm[e3 <= last ? e3 : last];
        uint2 a0 = *(const uint2*)&h[(size_t)p0.x * 64 + l * 4];
        uint2 a1 = *(const uint2*)&h[(size_t)p1.x * 64 + l * 4];
        uint2 a2 = *(const uint2*)&h[(size_t)p2.x * 64 + l * 4];
        uint2 a3 = *(const uint2*)&h[(size_t)p3.x * 64 + l * 4];
        float w0 = e0 <= last ? __int_as_float(p0.y) : 0.f;
        float w1 = e1 <= last ? __int_as_float(p1.y) : 0.f;
        float w2 = e2 <= last ? __int_as_float(p2.y) : 0.f;
        float w3 = e3 <= last ? __int_as_float(p3.y) : 0.f;
        acc4(acc, a0, w0);
        acc4(acc, a1, w1);
        acc4(acc, a2, w2);
        acc4(acc, a3, w3);
    }
#pragma unroll
    for (int i = 0; i < 4; i++) acc[i] += __shfl_xor(acc[i], 32);

    bool vf = l < 10;
    float m = vf ? fmaxf(fmaxf(acc[0], acc[1]), fmaxf(acc[2], acc[3]))
                 : -__builtin_inff();
#pragma unroll
    for (int off = 1; off < 64; off <<= 1) m = fmaxf(m, __shfl_xor(m, off));
    float s = 0.f;
    if (lane < 10)
        s = expf(acc[0] - m) + expf(acc[1] - m) + expf(acc[2] - m) + expf(acc[3] - m);
#pragma unroll
    for (int off = 1; off < 64; off <<= 1) s += __shfl_xor(s, off);
    float ls = m + logf(s);
    if (lane < 10) {
        float4 o = make_float4(acc[0] - ls, acc[1] - ls, acc[2] - ls, acc[3] - ls);
        *(float4*)&out[(size_t)node * 40 + lane * 4] = o;
    }
}

extern "C" void kernel_launch(void* const* d_in, const int* in_sizes, int n_in,
                              void* d_out, int out_size, void* d_ws, size_t ws_size,
                              hipStream_t stream) {
    const float* x  = (const float*)d_in[0];
    const int*   src = (const int*)d_in[1];
    const int*   tgt = (const int*)d_in[2];
    const float* ew  = (const float*)d_in[3];
    const float* W0 = (const float*)d_in[4];
    const float* b0 = (const float*)d_in[5];
    const float* W1 = (const float*)d_in[6];
    const float* b1 = (const float*)d_in[7];
    const float* W2 = (const float*)d_in[8];
    const float* b2 = (const float*)d_in[9];
    const float* W3 = (const float*)d_in[10];
    const float* b3 = (const float*)d_in[11];

    const int N = in_sizes[0] / 256;
    const int E = in_sizes[1];
    const int NSC = (N + SC_NODES - 1) >> SC_SHIFT;  // 391 for N=100k

    char* ws = (char*)d_ws;
    size_t off = 0;
    auto alloc = [&](size_t bytes) -> void* {
        void* p = ws + off;
        off = (off + bytes + 255) & ~(size_t)255;
        return p;
    };
    unsigned short* XCb = (unsigned short*)alloc((size_t)N * 128 * 2);
    // Hb region also hosts CSR staging (dead before first gemm): E*8 + E*1
    size_t hbytes = (size_t)N * 128 * 2;
    size_t sbytes = (size_t)E * 9 + 256;
    char* hbuf = (char*)alloc(hbytes > sbytes ? hbytes : sbytes);
    unsigned short* Hb = (unsigned short*)hbuf;
    int2* st_srcw = (int2*)hbuf;                               // E*8
    unsigned char* st_t8 = (unsigned char*)(hbuf + (size_t)E * 8);  // E*1
    // XAb aliases H40b (XAb dead after L2 agg)
    char* buf1 = (char*)alloc((size_t)N * 128 * 2);
    unsigned short* XAb  = (unsigned short*)buf1;
    unsigned short* H40b = (unsigned short*)buf1;
    unsigned short* XBb  = (unsigned short*)alloc((size_t)N * 128 * 2);
    int*   rowptr    = (int*)alloc((size_t)(N + 1) * 4);
    int*   chunkTot  = (int*)alloc(512 * 4);
    int*   chunkStart= (int*)alloc(520 * 4);
    int*   chunkCur  = (int*)alloc(512 * 32 * 4);  // padded 128B/counter
    int2*  perm      = (int2*)alloc((size_t)E * 8);
    unsigned short* Wt0 = (unsigned short*)alloc(256 * 128 * 2);
    unsigned short* Wt1 = (unsigned short*)alloc(128 * 128 * 2);
    unsigned short* Wt2 = (unsigned short*)alloc(128 * 128 * 2);
    unsigned short* Wt3 = (unsigned short*)alloc(48 * 128 * 2);
    (void)ws_size;

    float* logits = (float*)d_out;

    // weight prep + chunkTot zero (must precede k_count)
    k_wtrans_all<<<(71680 + 255) / 256, 256, 0, stream>>>(W0, W1, W2, W3,
                                                          Wt0, Wt1, Wt2, Wt3,
                                                          chunkTot);
    // CSR build
    k_count<<<(E + 4095) / 4096, 256, 0, stream>>>(tgt, chunkTot, E, NSC);
    k_scanB<<<1, 512, 0, stream>>>(chunkTot, chunkStart, chunkCur, E, NSC);
    k_bucket<<<(E + 8191) / 8192, 512, 0, stream>>>(src, tgt, ew, chunkCur,
                                                    st_srcw, st_t8, E);
    k_fill2<<<NSC, 256, 0, stream>>>(st_srcw, st_t8, chunkStart, rowptr, perm,
                                     N, E, NSC);

    const int gGemm = (N + 127) / 128;
    const int gWave = (N + 3) / 4;

    // L0 (reads fp32 x directly)
    k_gemm_mfma<256, 1><<<gGemm, 256, 0, stream>>>(x, Wt0, b0, Hb, N);
    k_agg128<<<gWave, 256, 0, stream>>>(Hb, rowptr, perm, nullptr, XAb, N);
    // L1
    k_gemm_mfma<128, 0><<<gGemm, 256, 0, stream>>>(XAb, Wt1, b1, Hb, N);
    k_agg128<<<gWave, 256, 0, stream>>>(Hb, rowptr, perm, nullptr, XBb, N);
    // L2 (+residual XAb) -> XCb
    k_gemm_mfma<128, 0><<<gGemm, 256, 0, stream>>>(XBb, Wt2, b2, Hb, N);
    k_agg128<<<gWave, 256, 0, stream>>>(Hb, rowptr, perm, XAb, XCb, N);
    // L3
    k_gemm40_mfma<<<gGemm, 256, 0, stream>>>(XCb, Wt3, b3, H40b, N);
    k_agg40_lsm<<<gWave, 256, 0, stream>>>(H40b, rowptr, perm, logits, N);
}

// Round 7
// 517.976 us; speedup vs baseline: 2.4888x; 1.0515x over previous
//
#include <hip/hip_runtime.h>
#include <hip/hip_bf16.h>

// ---------------------------------------------------------------------------
// RESK2 4-layer GCN on MI355X — round 7.
//  - perm packed to 4B/edge: (bf16(w)<<17)|src  (w>=0 so bf16 sign bit = 0;
//    src < 2^17). Halves edge-stream bytes everywhere.
//  - agg40: 16-lane groups, accesses confined to the row's single 128B line.
//  CSR: wtrans(+zero) -> count -> scanB -> bucket -> fill2 (single-writer sort)
//  L0..L3 unchanged structure (MFMA gemms, quarter-wave pull agg).
// ---------------------------------------------------------------------------

typedef __attribute__((ext_vector_type(8))) short short8;
typedef __attribute__((ext_vector_type(4))) float float4v;

#define SC_SHIFT 8              // 256 nodes per sub-chunk
#define SC_NODES 256
#define FILL_CAP 12288          // LDS edge capacity in fill2 (mean ~4096)
#define SRC_MASK 0x1FFFF        // 17 bits (N=100000 < 131072)

static __device__ __forceinline__ float bf2f_lo(unsigned int v) {
    return __uint_as_float(v << 16);
}
static __device__ __forceinline__ float bf2f_hi(unsigned int v) {
    return __uint_as_float(v & 0xffff0000u);
}
static __device__ __forceinline__ unsigned short f2bf(float f) {
    unsigned int u = __float_as_uint(f);
    u = (u + 0x7fffu + ((u >> 16) & 1u)) >> 16;  // RNE
    return (unsigned short)u;
}
static __device__ __forceinline__ unsigned int packbf(float a, float b) {
    return (unsigned int)f2bf(a) | ((unsigned int)f2bf(b) << 16);
}
static __device__ __forceinline__ float pw_w(unsigned int pe) {
    return __uint_as_float((pe >> 17) << 16);
}

static __device__ __forceinline__ void acc8(float* acc, uint4 v, float wt) {
    acc[0] = fmaf(bf2f_lo(v.x), wt, acc[0]);
    acc[1] = fmaf(bf2f_hi(v.x), wt, acc[1]);
    acc[2] = fmaf(bf2f_lo(v.y), wt, acc[2]);
    acc[3] = fmaf(bf2f_hi(v.y), wt, acc[3]);
    acc[4] = fmaf(bf2f_lo(v.z), wt, acc[4]);
    acc[5] = fmaf(bf2f_hi(v.z), wt, acc[5]);
    acc[6] = fmaf(bf2f_lo(v.w), wt, acc[6]);
    acc[7] = fmaf(bf2f_hi(v.w), wt, acc[7]);
}
static __device__ __forceinline__ void acc4(float* acc, uint2 v, float wt) {
    acc[0] = fmaf(bf2f_lo(v.x), wt, acc[0]);
    acc[1] = fmaf(bf2f_hi(v.x), wt, acc[1]);
    acc[2] = fmaf(bf2f_lo(v.y), wt, acc[2]);
    acc[3] = fmaf(bf2f_hi(v.y), wt, acc[3]);
}

// --------------------- CSR stage 1: bucket histogram -----------------------
__global__ __launch_bounds__(256) void k_count(const int* __restrict__ tgt,
                                               int* __restrict__ chunkTot,
                                               int E, int NSC) {
    __shared__ int hist[512];
    const int tid = threadIdx.x;
    hist[tid] = 0;
    hist[tid + 256] = 0;
    __syncthreads();
#pragma unroll
    for (int r = 0; r < 4; r++) {
        int e = blockIdx.x * 4096 + r * 1024 + tid * 4;
        if (e + 3 < E) {
            int4 tv = *(const int4*)&tgt[e];
            atomicAdd(&hist[tv.x >> SC_SHIFT], 1);
            atomicAdd(&hist[tv.y >> SC_SHIFT], 1);
            atomicAdd(&hist[tv.z >> SC_SHIFT], 1);
            atomicAdd(&hist[tv.w >> SC_SHIFT], 1);
        } else {
            for (int j = 0; j < 4; j++)
                if (e + j < E) atomicAdd(&hist[tgt[e + j] >> SC_SHIFT], 1);
        }
    }
    __syncthreads();
    for (int i = tid; i < NSC; i += 256) {
        int c = hist[i];
        if (c) atomicAdd(&chunkTot[i], c);
    }
}

// --------------------- CSR stage 2: bucket prefix scan ---------------------
__global__ __launch_bounds__(512) void k_scanB(const int* __restrict__ chunkTot,
                                               int* __restrict__ chunkStart,
                                               int* __restrict__ chunkCur,
                                               int E, int NSC) {
    __shared__ int sm[512];
    const int tid = threadIdx.x;
    int v = (tid < NSC) ? chunkTot[tid] : 0;
    sm[tid] = v;
    __syncthreads();
    for (int off = 1; off < 512; off <<= 1) {
        int t = (tid >= off) ? sm[tid - off] : 0;
        __syncthreads();
        sm[tid] += t;
        __syncthreads();
    }
    int excl = sm[tid] - v;
    if (tid < NSC) {
        chunkStart[tid] = excl;
        chunkCur[tid * 32] = excl;
    }
    if (tid == 0) chunkStart[NSC] = E;
}

// --------------------- CSR stage 3: bucket into staging --------------------
__global__ __launch_bounds__(512) void k_bucket(const int* __restrict__ src,
                                                const int* __restrict__ tgt,
                                                const float* __restrict__ ew,
                                                int* __restrict__ chunkCur,
                                                unsigned int* __restrict__ st_pw,
                                                unsigned char* __restrict__ st_t8,
                                                int E) {
    __shared__ int cnt[512];
    __shared__ int rk[512];
    __shared__ int bbase[512];
    const int tid = threadIdx.x;
    cnt[tid] = 0;
    rk[tid] = 0;
    __syncthreads();

    int t16[16];
    unsigned int p16[16];
#pragma unroll
    for (int r = 0; r < 4; r++) {
        int e = blockIdx.x * 8192 + r * 2048 + tid * 4;
        if (e + 3 < E) {
            int4 tv = *(const int4*)&tgt[e];
            int4 sv = *(const int4*)&src[e];
            float4 wv = *(const float4*)&ew[e];
            t16[r * 4 + 0] = tv.x; t16[r * 4 + 1] = tv.y;
            t16[r * 4 + 2] = tv.z; t16[r * 4 + 3] = tv.w;
            p16[r * 4 + 0] = ((unsigned int)f2bf(wv.x) << 17) | (unsigned int)sv.x;
            p16[r * 4 + 1] = ((unsigned int)f2bf(wv.y) << 17) | (unsigned int)sv.y;
            p16[r * 4 + 2] = ((unsigned int)f2bf(wv.z) << 17) | (unsigned int)sv.z;
            p16[r * 4 + 3] = ((unsigned int)f2bf(wv.w) << 17) | (unsigned int)sv.w;
        } else {
            for (int j = 0; j < 4; j++) {
                int ee = e + j;
                t16[r * 4 + j] = (ee < E) ? tgt[ee] : -1;
                p16[r * 4 + j] = (ee < E)
                    ? (((unsigned int)f2bf(ew[ee]) << 17) | (unsigned int)src[ee])
                    : 0u;
            }
        }
    }
#pragma unroll
    for (int j = 0; j < 16; j++)
        if (t16[j] >= 0) atomicAdd(&cnt[t16[j] >> SC_SHIFT], 1);
    __syncthreads();
    {
        int c = cnt[tid];
        bbase[tid] = c ? atomicAdd(&chunkCur[tid * 32], c) : 0;
    }
    __syncthreads();
#pragma unroll
    for (int j = 0; j < 16; j++) {
        if (t16[j] >= 0) {
            int c = t16[j] >> SC_SHIFT;
            int pos = bbase[c] + atomicAdd(&rk[c], 1);
            st_pw[pos] = p16[j];
            st_t8[pos] = (unsigned char)(t16[j] & (SC_NODES - 1));
        }
    }
}

// --------------------- CSR stage 4: per-bucket sort ------------------------
__global__ __launch_bounds__(256) void k_fill2(const unsigned int* __restrict__ st_pw,
                                               const unsigned char* __restrict__ st_t8,
                                               const int* __restrict__ chunkStart,
                                               int* __restrict__ rowptr,
                                               unsigned int* __restrict__ perm,
                                               int N, int E, int NSC) {
    __shared__ int lhist[SC_NODES];
    __shared__ int lcur[SC_NODES];
    __shared__ unsigned int ledge[FILL_CAP];
    const int tid = threadIdx.x;
    const int b = blockIdx.x;
    const int n0 = b << SC_SHIFT;
    const int nlocal = min(SC_NODES, N - n0);
    const int sstart = chunkStart[b];
    const int send = chunkStart[b + 1];
    const int cnt = send - sstart;

    lhist[tid] = 0;
    __syncthreads();
    for (int e = sstart + tid; e < send; e += 256)
        atomicAdd(&lhist[st_t8[e]], 1);
    __syncthreads();
    int v = lhist[tid];
    __syncthreads();
    lhist[tid] = v;
    __syncthreads();
    for (int off = 1; off < 256; off <<= 1) {
        int t = (tid >= off) ? lhist[tid - off] : 0;
        __syncthreads();
        lhist[tid] += t;
        __syncthreads();
    }
    int excl = lhist[tid] - v;
    if (tid < nlocal) rowptr[n0 + tid] = sstart + excl;
    if (b == NSC - 1 && tid == 0) rowptr[N] = E;
    lcur[tid] = excl;
    __syncthreads();

    if (cnt <= FILL_CAP) {
        for (int e = sstart + tid; e < send; e += 256) {
            int lt = st_t8[e];
            int pos = atomicAdd(&lcur[lt], 1);
            ledge[pos] = st_pw[e];
        }
        __syncthreads();
        for (int i = tid; i < cnt; i += 256) perm[sstart + i] = ledge[i];
    } else {
        for (int e = sstart + tid; e < send; e += 256) {
            int lt = st_t8[e];
            int pos = atomicAdd(&lcur[lt], 1);
            perm[sstart + pos] = st_pw[e];
        }
    }
}

// ----------------------------- weight prep --------------------------------
__global__ __launch_bounds__(256) void k_wtrans_all(
    const float* __restrict__ W0, const float* __restrict__ W1,
    const float* __restrict__ W2, const float* __restrict__ W3,
    unsigned short* __restrict__ Wt0, unsigned short* __restrict__ Wt1,
    unsigned short* __restrict__ Wt2, unsigned short* __restrict__ Wt3,
    int* __restrict__ chunkTot) {
    int idx = blockIdx.x * 256 + threadIdx.x;
    if (idx < 512) chunkTot[idx] = 0;
    if (idx < 32768) {
        int c = idx >> 8, k = idx & 255;
        Wt0[idx] = f2bf(W0[k * 128 + c]);
    } else if (idx < 49152) {
        int i = idx - 32768;
        int c = i >> 7, k = i & 127;
        Wt1[i] = f2bf(W1[k * 128 + c]);
    } else if (idx < 65536) {
        int i = idx - 49152;
        int c = i >> 7, k = i & 127;
        Wt2[i] = f2bf(W2[k * 128 + c]);
    } else if (idx < 71680) {
        int i = idx - 65536;
        int c = i >> 7, k = i & 127;
        Wt3[i] = (c < 40) ? f2bf(W3[k * 40 + c]) : 0;
    }
}

// ---------------------------------------------------------------------------
// MFMA GEMM: C[N,128](bf16) = A[N,K] @ Wt[128][K] + b. 128x128/block.
// ---------------------------------------------------------------------------
template <int K, int AF32>
__global__ __launch_bounds__(256) void k_gemm_mfma(const void* __restrict__ Av,
                                                   const unsigned short* __restrict__ Wt,
                                                   const float* __restrict__ bias,
                                                   unsigned short* __restrict__ C, int N) {
    __shared__ unsigned short As[128 * 40];
    __shared__ unsigned short Bs[128 * 40];
    const unsigned short* A16 = (const unsigned short*)Av;
    const float* A32 = (const float*)Av;
    const int tid = threadIdx.x;
    const int wave = tid >> 6, lane = tid & 63;
    const int quad = lane >> 4, l15 = lane & 15;
    const int rowBase = blockIdx.x * 128;

    const float4v z = {0.f, 0.f, 0.f, 0.f};
    float4v acc[2][8];
#pragma unroll
    for (int i = 0; i < 2; i++)
#pragma unroll
        for (int j = 0; j < 8; j++) acc[i][j] = z;

    for (int k0 = 0; k0 < K; k0 += 32) {
#pragma unroll
        for (int i = 0; i < 2; i++) {
            int t = i * 256 + tid;
            int r = t >> 2;
            int kc = t & 3;
            int rg = rowBase + r;
            rg = rg < N ? rg : N - 1;
            uint4 va;
            if (AF32) {
                float4 f0 = *(const float4*)&A32[(size_t)rg * K + k0 + kc * 8];
                float4 f1 = *(const float4*)&A32[(size_t)rg * K + k0 + kc * 8 + 4];
                va.x = packbf(f0.x, f0.y);
                va.y = packbf(f0.z, f0.w);
                va.z = packbf(f1.x, f1.y);
                va.w = packbf(f1.z, f1.w);
            } else {
                va = *(const uint4*)&A16[(size_t)rg * K + k0 + kc * 8];
            }
            *(uint4*)&As[r * 40 + kc * 8] = va;
            uint4 vb = *(const uint4*)&Wt[(size_t)r * K + k0 + kc * 8];
            *(uint4*)&Bs[r * 40 + kc * 8] = vb;
        }
        __syncthreads();

        short8 a0 = *(const short8*)&As[(wave * 32 + l15) * 40 + quad * 8];
        short8 a1 = *(const short8*)&As[(wave * 32 + 16 + l15) * 40 + quad * 8];
#pragma unroll
        for (int c = 0; c < 8; c++) {
            short8 b = *(const short8*)&Bs[(c * 16 + l15) * 40 + quad * 8];
            acc[0][c] = __builtin_amdgcn_mfma_f32_16x16x32_bf16(a0, b, acc[0][c], 0, 0, 0);
            acc[1][c] = __builtin_amdgcn_mfma_f32_16x16x32_bf16(a1, b, acc[1][c], 0, 0, 0);
        }
        __syncthreads();
    }

#pragma unroll
    for (int rt = 0; rt < 2; rt++) {
#pragma unroll
        for (int c = 0; c < 8; c++) {
            int col = c * 16 + l15;
            float bv = bias[col];
#pragma unroll
            for (int i = 0; i < 4; i++) {
                int row = rowBase + wave * 32 + rt * 16 + quad * 4 + i;
                if (row < N) C[(size_t)row * 128 + col] = f2bf(acc[rt][c][i] + bv);
            }
        }
    }
}

// MFMA gemm40: H40[N,64-stride](bf16, cols<40) = A[N,128](bf16) @ Wt3 + b3.
__global__ __launch_bounds__(256) void k_gemm40_mfma(const unsigned short* __restrict__ A,
                                                     const unsigned short* __restrict__ Wt3,
                                                     const float* __restrict__ bias,
                                                     unsigned short* __restrict__ C, int N) {
    __shared__ unsigned short As[128 * 40];
    __shared__ unsigned short Bs[48 * 136];
    const int tid = threadIdx.x;
    const int wave = tid >> 6, lane = tid & 63;
    const int quad = lane >> 4, l15 = lane & 15;
    const int rowBase = blockIdx.x * 128;

    for (int t = tid; t < 48 * 16; t += 256) {
        int r = t >> 4, kc = t & 15;
        uint4 v = *(const uint4*)&Wt3[r * 128 + kc * 8];
        *(uint4*)&Bs[r * 136 + kc * 8] = v;
    }

    const float4v z = {0.f, 0.f, 0.f, 0.f};
    float4v acc[2][3];
#pragma unroll
    for (int i = 0; i < 2; i++)
#pragma unroll
        for (int j = 0; j < 3; j++) acc[i][j] = z;

    for (int k0 = 0; k0 < 128; k0 += 32) {
#pragma unroll
        for (int i = 0; i < 2; i++) {
            int t = i * 256 + tid;
            int r = t >> 2;
            int kc = t & 3;
            int rg = rowBase + r;
            rg = rg < N ? rg : N - 1;
            uint4 va = *(const uint4*)&A[(size_t)rg * 128 + k0 + kc * 8];
            *(uint4*)&As[r * 40 + kc * 8] = va;
        }
        __syncthreads();

        short8 a0 = *(const short8*)&As[(wave * 32 + l15) * 40 + quad * 8];
        short8 a1 = *(const short8*)&As[(wave * 32 + 16 + l15) * 40 + quad * 8];
#pragma unroll
        for (int c = 0; c < 3; c++) {
            short8 b = *(const short8*)&Bs[(c * 16 + l15) * 136 + k0 + quad * 8];
            acc[0][c] = __builtin_amdgcn_mfma_f32_16x16x32_bf16(a0, b, acc[0][c], 0, 0, 0);
            acc[1][c] = __builtin_amdgcn_mfma_f32_16x16x32_bf16(a1, b, acc[1][c], 0, 0, 0);
        }
        __syncthreads();
    }

#pragma unroll
    for (int rt = 0; rt < 2; rt++) {
#pragma unroll
        for (int c = 0; c < 3; c++) {
            int col = c * 16 + l15;
            if (col < 40) {
                float bv = bias[col];
#pragma unroll
                for (int i = 0; i < 4; i++) {
                    int row = rowBase + wave * 32 + rt * 16 + quad * 4 + i;
                    if (row < N) C[(size_t)row * 64 + col] = f2bf(acc[rt][c][i] + bv);
                }
            }
        }
    }
}

// ---------------------------------------------------------------------------
// Pull aggregation F=128: one wave/node, quarter-wave per edge (packed perm).
// ---------------------------------------------------------------------------
__global__ __launch_bounds__(256) void k_agg128(const unsigned short* __restrict__ h,
                                                const int* __restrict__ rowptr,
                                                const unsigned int* __restrict__ perm,
                                                const unsigned short* __restrict__ resid,
                                                unsigned short* __restrict__ out, int N) {
    int node = (blockIdx.x * 256 + threadIdx.x) >> 6;
    if (node >= N) return;
    const int lane = threadIdx.x & 63;
    const int g = lane >> 4, l = lane & 15;
    const int beg = rowptr[node], end = rowptr[node + 1];
    const int last = end - 1;

    float acc[8] = {};
    for (int base = beg; base < end; base += 16) {
        int e0 = base + g, e1 = base + 4 + g, e2 = base + 8 + g, e3 = base + 12 + g;
        unsigned int p0 = perm[e0 <= last ? e0 : last];
        unsigned int p1 = perm[e1 <= last ? e1 : last];
        unsigned int p2 = perm[e2 <= last ? e2 : last];
        unsigned int p3 = perm[e3 <= last ? e3 : last];
        uint4 a0 = *(const uint4*)&h[(size_t)(p0 & SRC_MASK) * 128 + l * 8];
        uint4 a1 = *(const uint4*)&h[(size_t)(p1 & SRC_MASK) * 128 + l * 8];
        uint4 a2 = *(const uint4*)&h[(size_t)(p2 & SRC_MASK) * 128 + l * 8];
        uint4 a3 = *(const uint4*)&h[(size_t)(p3 & SRC_MASK) * 128 + l * 8];
        float w0 = e0 <= last ? pw_w(p0) : 0.f;
        float w1 = e1 <= last ? pw_w(p1) : 0.f;
        float w2 = e2 <= last ? pw_w(p2) : 0.f;
        float w3 = e3 <= last ? pw_w(p3) : 0.f;
        acc8(acc, a0, w0);
        acc8(acc, a1, w1);
        acc8(acc, a2, w2);
        acc8(acc, a3, w3);
    }

#pragma unroll
    for (int i = 0; i < 8; i++) {
        acc[i] += __shfl_xor(acc[i], 16);
        acc[i] += __shfl_xor(acc[i], 32);
    }

    if (g == 0) {
#pragma unroll
        for (int i = 0; i < 8; i++) acc[i] = fmaxf(acc[i], 0.f);
        if (resid) {
            uint4 rv = *(const uint4*)&resid[(size_t)node * 128 + l * 8];
            acc[0] += bf2f_lo(rv.x); acc[1] += bf2f_hi(rv.x);
            acc[2] += bf2f_lo(rv.y); acc[3] += bf2f_hi(rv.y);
            acc[4] += bf2f_lo(rv.z); acc[5] += bf2f_hi(rv.z);
            acc[6] += bf2f_lo(rv.w); acc[7] += bf2f_hi(rv.w);
        }
        uint4 o;
        o.x = packbf(acc[0], acc[1]);
        o.y = packbf(acc[2], acc[3]);
        o.z = packbf(acc[4], acc[5]);
        o.w = packbf(acc[6], acc[7]);
        *(uint4*)&out[(size_t)node * 128 + l * 8] = o;
    }
}

// ---------------------------------------------------------------------------
// Final layer: F=40 gather, 16-lane groups (4 edges per slot), all accesses
// inside the row's single aligned 128B line. Lanes l<10 valid (classes l*4..
// l*4+3); lanes 10..15 read in-row pad (finite garbage, masked). Fused lsm.
// ---------------------------------------------------------------------------
__global__ __launch_bounds__(256) void k_agg40_lsm(const unsigned short* __restrict__ h,
                                                   const int* __restrict__ rowptr,
                                                   const unsigned int* __restrict__ perm,
                                                   float* __restrict__ out, int N) {
    int node = (blockIdx.x * 256 + threadIdx.x) >> 6;
    if (node >= N) return;
    const int lane = threadIdx.x & 63;
    const int g = lane >> 4, l = lane & 15;
    const int beg = rowptr[node], end = rowptr[node + 1];
    const int last = end - 1;
    const int lc = l < 10 ? l : 0;  // lanes 10..15 alias lane 0 (discarded)

    float acc[4] = {};
    for (int base = beg; base < end; base += 16) {
        int e0 = base + g, e1 = base + 4 + g, e2 = base + 8 + g, e3 = base + 12 + g;
        unsigned int p0 = perm[e0 <= last ? e0 : last];
        unsigned int p1 = perm[e1 <= last ? e1 : last];
        unsigned int p2 = perm[e2 <= last ? e2 : last];
        unsigned int p3 = perm[e3 <= last ? e3 : last];
        uint2 a0 = *(const uint2*)&h[(size_t)(p0 & SRC_MASK) * 64 + lc * 4];
        uint2 a1 = *(const uint2*)&h[(size_t)(p1 & SRC_MASK) * 64 + lc * 4];
        uint2 a2 = *(const uint2*)&h[(size_t)(p2 & SRC_MASK) * 64 + lc * 4];
        uint2 a3 = *(const uint2*)&h[(size_t)(p3 & SRC_MASK) * 64 + lc * 4];
        float w0 = e0 <= last ? pw_w(p0) : 0.f;
        float w1 = e1 <= last ? pw_w(p1) : 0.f;
        float w2 = e2 <= last ? pw_w(p2) : 0.f;
        float w3 = e3 <= last ? pw_w(p3) : 0.f;
        acc4(acc, a0, w0);
        acc4(acc, a1, w1);
        acc4(acc, a2, w2);
        acc4(acc, a3, w3);
    }
#pragma unroll
    for (int i = 0; i < 4; i++) {
        acc[i] += __shfl_xor(acc[i], 16);
        acc[i] += __shfl_xor(acc[i], 32);
    }

    // log_softmax over 40 values: lanes l<10 (in every group) hold 4 each
    bool vf = l < 10;
    float m = vf ? fmaxf(fmaxf(acc[0], acc[1]), fmaxf(acc[2], acc[3]))
                 : -__builtin_inff();
#pragma unroll
    for (int off = 1; off < 16; off <<= 1) m = fmaxf(m, __shfl_xor(m, off));
    float s = vf ? (expf(acc[0] - m) + expf(acc[1] - m) +
                    expf(acc[2] - m) + expf(acc[3] - m))
                 : 0.f;
#pragma unroll
    for (int off = 1; off < 16; off <<= 1) s += __shfl_xor(s, off);
    float ls = m + logf(s);
    if (g == 0 && vf) {
        float4 o = make_float4(acc[0] - ls, acc[1] - ls, acc[2] - ls, acc[3] - ls);
        *(float4*)&out[(size_t)node * 40 + l * 4] = o;
    }
}

extern "C" void kernel_launch(void* const* d_in, const int* in_sizes, int n_in,
                              void* d_out, int out_size, void* d_ws, size_t ws_size,
                              hipStream_t stream) {
    const float* x  = (const float*)d_in[0];
    const int*   src = (const int*)d_in[1];
    const int*   tgt = (const int*)d_in[2];
    const float* ew  = (const float*)d_in[3];
    const float* W0 = (const float*)d_in[4];
    const float* b0 = (const float*)d_in[5];
    const float* W1 = (const float*)d_in[6];
    const float* b1 = (const float*)d_in[7];
    const float* W2 = (const float*)d_in[8];
    const float* b2 = (const float*)d_in[9];
    const float* W3 = (const float*)d_in[10];
    const float* b3 = (const float*)d_in[11];

    const int N = in_sizes[0] / 256;
    const int E = in_sizes[1];
    const int NSC = (N + SC_NODES - 1) >> SC_SHIFT;

    char* ws = (char*)d_ws;
    size_t off = 0;
    auto alloc = [&](size_t bytes) -> void* {
        void* p = ws + off;
        off = (off + bytes + 255) & ~(size_t)255;
        return p;
    };
    unsigned short* XCb = (unsigned short*)alloc((size_t)N * 128 * 2);
    // Hb region also hosts CSR staging (dead before first gemm): E*4 + E*1
    size_t hbytes = (size_t)N * 128 * 2;
    size_t sbytes = (size_t)E * 5 + 256;
    char* hbuf = (char*)alloc(hbytes > sbytes ? hbytes : sbytes);
    unsigned short* Hb = (unsigned short*)hbuf;
    unsigned int* st_pw = (unsigned int*)hbuf;                      // E*4
    unsigned char* st_t8 = (unsigned char*)(hbuf + (size_t)E * 4);  // E*1
    char* buf1 = (char*)alloc((size_t)N * 128 * 2);
    unsigned short* XAb  = (unsigned short*)buf1;
    unsigned short* H40b = (unsigned short*)buf1;
    unsigned short* XBb  = (unsigned short*)alloc((size_t)N * 128 * 2);
    int*   rowptr    = (int*)alloc((size_t)(N + 1) * 4);
    int*   chunkTot  = (int*)alloc(512 * 4);
    int*   chunkStart= (int*)alloc(520 * 4);
    int*   chunkCur  = (int*)alloc(512 * 32 * 4);
    unsigned int* perm = (unsigned int*)alloc((size_t)E * 4);
    unsigned short* Wt0 = (unsigned short*)alloc(256 * 128 * 2);
    unsigned short* Wt1 = (unsigned short*)alloc(128 * 128 * 2);
    unsigned short* Wt2 = (unsigned short*)alloc(128 * 128 * 2);
    unsigned short* Wt3 = (unsigned short*)alloc(48 * 128 * 2);
    (void)ws_size;

    float* logits = (float*)d_out;

    k_wtrans_all<<<(71680 + 255) / 256, 256, 0, stream>>>(W0, W1, W2, W3,
                                                          Wt0, Wt1, Wt2, Wt3,
                                                          chunkTot);
    k_count<<<(E + 4095) / 4096, 256, 0, stream>>>(tgt, chunkTot, E, NSC);
    k_scanB<<<1, 512, 0, stream>>>(chunkTot, chunkStart, chunkCur, E, NSC);
    k_bucket<<<(E + 8191) / 8192, 512, 0, stream>>>(src, tgt, ew, chunkCur,
                                                    st_pw, st_t8, E);
    k_fill2<<<NSC, 256, 0, stream>>>(st_pw, st_t8, chunkStart, rowptr, perm,
                                     N, E, NSC);

    const int gGemm = (N + 127) / 128;
    const int gWave = (N + 3) / 4;

    // L0 (reads fp32 x directly)
    k_gemm_mfma<256, 1><<<gGemm, 256, 0, stream>>>(x, Wt0, b0, Hb, N);
    k_agg128<<<gWave, 256, 0, stream>>>(Hb, rowptr, perm, nullptr, XAb, N);
    // L1
    k_gemm_mfma<128, 0><<<gGemm, 256, 0, stream>>>(XAb, Wt1, b1, Hb, N);
    k_agg128<<<gWave, 256, 0, stream>>>(Hb, rowptr, perm, nullptr, XBb, N);
    // L2 (+residual XAb) -> XCb
    k_gemm_mfma<128, 0><<<gGemm, 256, 0, stream>>>(XBb, Wt2, b2, Hb, N);
    k_agg128<<<gWave, 256, 0, stream>>>(Hb, rowptr, perm, XAb, XCb, N);
    // L3
    k_gemm40_mfma<<<gGemm, 256, 0, stream>>>(XCb, Wt3, b3, H40b, N);
    k_agg40_lsm<<<gWave, 256, 0, stream>>>(H40b, rowptr, perm, logits, N);
}